// Round 3
// baseline (333.079 us; speedup 1.0000x reference)
//
#include <hip/hip_runtime.h>
#include <hip/hip_bf16.h>

// ---- constants ----
// B=4, S=2048, E=1024, H=16, D=64, scale = 0.125, LN eps 1e-5
#define LOG2E 1.44269504088896340736f

typedef __attribute__((ext_vector_type(8)))  short  short8;
typedef __attribute__((ext_vector_type(4)))  float  f32x4;
typedef __attribute__((ext_vector_type(16))) float  f32x16;

__device__ __forceinline__ unsigned short f2bf(float f) {
  unsigned u = __builtin_bit_cast(unsigned, f);
  return (unsigned short)((u + 0x8000u) >> 16);
}
// pack two fp32 -> bf16x2 (compiler emits v_cvt_pk_bf16_f32)
__device__ __forceinline__ unsigned cvtpk(float a, float b) {
  unsigned short lo = __builtin_bit_cast(unsigned short, __float2bfloat16(a));
  unsigned short hi = __builtin_bit_cast(unsigned short, __float2bfloat16(b));
  return (unsigned)lo | ((unsigned)hi << 16);
}
__device__ __forceinline__ void gl16(const void* g, void* l) {
  __builtin_amdgcn_global_load_lds(
      (const __attribute__((address_space(1))) void*)g,
      (__attribute__((address_space(3))) void*)l, 16, 0, 0);
}
// tree max of 16
__device__ __forceinline__ float vmax16(f32x16 s) {
  float a[8];
#pragma unroll
  for (int j = 0; j < 8; j++) a[j] = fmaxf(s[2 * j], s[2 * j + 1]);
#pragma unroll
  for (int j = 0; j < 4; j++) a[j] = fmaxf(a[j], a[j + 4]);
  return fmaxf(fmaxf(a[0], a[1]), fmaxf(a[2], a[3]));
}

// ---------------- prep kernels ----------------

// W[e][f] fp32 -> Wt[f][e] bf16 (rotation & entangle; z selects)
__global__ __launch_bounds__(256) void prep_wt(const float* __restrict__ R,
                                               const float* __restrict__ En,
                                               unsigned short* __restrict__ Rt,
                                               unsigned short* __restrict__ Et) {
  const float* src = blockIdx.z ? En : R;
  unsigned short* dst = blockIdx.z ? Et : Rt;
  __shared__ unsigned short t[64][65];
  int e0 = blockIdx.y * 64, f0 = blockIdx.x * 64;
  int tid = threadIdx.x;
  int r = tid >> 2, c4 = (tid & 3) * 16;
#pragma unroll
  for (int j = 0; j < 16; j += 4) {
    float4 v = *(const float4*)(src + (size_t)(e0 + r) * 1024 + f0 + c4 + j);
    t[c4 + j + 0][r] = f2bf(v.x);
    t[c4 + j + 1][r] = f2bf(v.y);
    t[c4 + j + 2][r] = f2bf(v.z);
    t[c4 + j + 3][r] = f2bf(v.w);
  }
  __syncthreads();
  short8 o0, o1;
#pragma unroll
  for (int j = 0; j < 8; j++) {
    o0[j] = (short)t[r][c4 + j];
    o1[j] = (short)t[r][c4 + 8 + j];
  }
  *(short8*)(dst + (size_t)(f0 + r) * 1024 + e0 + c4) = o0;
  *(short8*)(dst + (size_t)(f0 + r) * 1024 + e0 + c4 + 8) = o1;
}

// x -> Vt[(bh*64+d)][s] bf16 AND xb (linear bf16 copy) in one pass
__global__ __launch_bounds__(256) void prep_vt(const float* __restrict__ x,
                                               unsigned short* __restrict__ vt,
                                               unsigned short* __restrict__ xb) {
  int bh = blockIdx.y, b = bh >> 4, h = bh & 15;
  int s0 = blockIdx.x * 64;
  __shared__ unsigned short t[64][65];   // [d][s]
  int tid = threadIdx.x;
  int r = tid >> 2, c4 = (tid & 3) * 16;
#pragma unroll
  for (int j = 0; j < 16; j += 4) {
    float4 v = *(const float4*)(x + (size_t)(b * 2048 + s0 + r) * 1024 + h * 64 + c4 + j);
    ushort4 o;
    o.x = f2bf(v.x); o.y = f2bf(v.y); o.z = f2bf(v.z); o.w = f2bf(v.w);
    t[c4 + j + 0][r] = o.x;
    t[c4 + j + 1][r] = o.y;
    t[c4 + j + 2][r] = o.z;
    t[c4 + j + 3][r] = o.w;
    *(ushort4*)(xb + (size_t)(b * 2048 + s0 + r) * 1024 + h * 64 + c4 + j) = o;
  }
  __syncthreads();
  short8 o0, o1;
#pragma unroll
  for (int j = 0; j < 8; j++) {
    o0[j] = (short)t[r][c4 + j];
    o1[j] = (short)t[r][c4 + 8 + j];
  }
  *(short8*)(vt + (size_t)(bh * 64 + r) * 2048 + s0 + c4) = o0;
  *(short8*)(vt + (size_t)(bh * 64 + r) * 2048 + s0 + c4 + 8) = o1;
}

// ---------------- projection GEMM (m97 structure) ----------------
__global__ __launch_bounds__(256) void gemm_qk(const unsigned short* __restrict__ A,
                                               const unsigned short* __restrict__ Bw,
                                               unsigned short* __restrict__ out,
                                               float scale) {
  int m0 = blockIdx.x * 128, n0 = blockIdx.y * 128;
  int tid = threadIdx.x;
  int w = tid >> 6, l = tid & 63;
  int wr = w >> 1, wc = w & 1;
  int l15 = l & 15, lq = l >> 4;

  __shared__ unsigned short As[128 * 64];
  __shared__ unsigned short Bs[128 * 64];

  f32x4 acc[4][4] = {};

  for (int k0 = 0; k0 < 1024; k0 += 64) {
    __syncthreads();
#pragma unroll
    for (int i = 0; i < 4; i++) {
      int row = i * 32 + (tid >> 3), ch = tid & 7;
      gl16(A  + (size_t)(m0 + row) * 1024 + k0 + ((ch ^ (row & 7)) << 3),
           (char*)As + i * 4096 + w * 1024);
      gl16(Bw + (size_t)(n0 + row) * 1024 + k0 + ((ch ^ (row & 7)) << 3),
           (char*)Bs + i * 4096 + w * 1024);
    }
    __syncthreads();

    short8 af[4][2], bfr[4][2];
#pragma unroll
    for (int mf = 0; mf < 4; mf++)
#pragma unroll
      for (int kk = 0; kk < 2; kk++) {
        int row = wr * 64 + mf * 16 + l15;
        int kb2 = (kk * 32 + lq * 8) * 2;
        af[mf][kk] = *(const short8*)((const char*)As + row * 128 + (kb2 ^ ((row & 7) << 4)));
      }
#pragma unroll
    for (int nf = 0; nf < 4; nf++)
#pragma unroll
      for (int kk = 0; kk < 2; kk++) {
        int row = wc * 64 + nf * 16 + l15;
        int kb2 = (kk * 32 + lq * 8) * 2;
        bfr[nf][kk] = *(const short8*)((const char*)Bs + row * 128 + (kb2 ^ ((row & 7) << 4)));
      }
#pragma unroll
    for (int mf = 0; mf < 4; mf++)
#pragma unroll
      for (int nf = 0; nf < 4; nf++)
#pragma unroll
        for (int kk = 0; kk < 2; kk++)
          acc[mf][nf] = __builtin_amdgcn_mfma_f32_16x16x32_bf16(
              af[mf][kk], bfr[nf][kk], acc[mf][nf], 0, 0, 0);
  }

#pragma unroll
  for (int mf = 0; mf < 4; mf++)
#pragma unroll
    for (int nf = 0; nf < 4; nf++)
#pragma unroll
      for (int r = 0; r < 4; r++) {
        int grow = m0 + wr * 64 + mf * 16 + lq * 4 + r;
        int gcol = n0 + wc * 64 + nf * 16 + l15;
        out[(size_t)grow * 1024 + gcol] = f2bf(acc[mf][nf][r] * scale);
      }
}

// ---------------- flash attention ----------------
// 256 thr = 4 waves, wave owns 32 q-rows. Swapped QK^T (mfma(K,Q), 32x32x16).
// K double-buffered in LDS; V direct from global (L2-resident per head).
// P-frag exchange via cvt_pk + permlane32_swap:
//   swap(a,b): ret[0] = {l<32: a(l),    l>=32: b(l-32)}
//              ret[1] = {l<32: a(l+32), l>=32: b(l)}
// need u[0] = {l<32: P0(l), l>=32: P2(l-32)} -> swap(P0,P2)[0]; u[2] -> [1].
__global__ __launch_bounds__(256) void attn_k(const unsigned short* __restrict__ Q,
                                              const unsigned short* __restrict__ K,
                                              const unsigned short* __restrict__ VT,
                                              float* __restrict__ ctx) {
  int f = blockIdx.x;
  int bh = ((f >> 7) << 3) | (f & 7);   // cluster a head's q-tiles on one XCD
  int qt = (f >> 3) & 15;
  int b = bh >> 4, h = bh & 15;
  int q0 = qt * 128;
  int tid = threadIdx.x;
  int w = tid >> 6, l = tid & 63;
  int lh = l >> 5, l31 = l & 31;

  __shared__ unsigned short Kl[2 * 128 * 64];   // double-buffered, swizzled

  // Q fragments (B-operand): lane holds Q[q=l31][d = dk*16 + lh*8 + j]
  int qrow = q0 + w * 32 + l31;
  const unsigned short* qp = Q + (size_t)(b * 2048 + qrow) * 1024 + h * 64;
  short8 qf[4];
#pragma unroll
  for (int dk = 0; dk < 4; dk++) qf[dk] = *(const short8*)(qp + dk * 16 + lh * 8);

  // V base: lane reads VT[d = df*32 + l31][t' ...] with lh*8 element offset
  const unsigned short* vrow = VT + (size_t)(bh * 64 + l31) * 2048 + lh * 8;

  f32x16 cacc[2] = {};
  float mrun = -INFINITY, lsum = 0.f;

#define STAGEK(buf, tt)                                                       \
  {                                                                           \
    _Pragma("unroll") for (int i_ = 0; i_ < 4; i_++) {                        \
      int row_ = i_ * 32 + (tid >> 3), ch_ = tid & 7;                         \
      gl16(K + (size_t)(b * 2048 + (tt) + row_) * 1024 + h * 64 +             \
               ((ch_ ^ (row_ & 7)) << 3),                                     \
           (char*)Kl + (buf) * 16384 + i_ * 4096 + w * 1024);                 \
    }                                                                         \
  }

  STAGEK(0, 0);
  __syncthreads();
  int cur = 0;

  for (int t0c = 0; t0c < 16; t0c++) {
    int t0 = t0c * 128;
    if (t0c < 15) STAGEK(cur ^ 1, t0 + 128);

    const char* Kb = (const char*)Kl + cur * 16384;

    // ---- QK^T: S^T[t'][q] ----
    f32x16 sacc[4] = {};
    __builtin_amdgcn_s_setprio(1);
#pragma unroll
    for (int tf = 0; tf < 4; tf++) {
#pragma unroll
      for (int dk = 0; dk < 4; dk++) {
        int row = tf * 32 + l31;
        int kb2 = (dk * 16 + lh * 8) * 2;
        short8 kf = *(const short8*)(Kb + row * 128 + (kb2 ^ ((row & 7) << 4)));
        sacc[tf] = __builtin_amdgcn_mfma_f32_32x32x16_bf16(kf, qf[dk], sacc[tf], 0, 0, 0);
      }
    }
    __builtin_amdgcn_s_setprio(0);

    // prefetch V fragments for tf=0 (independent of softmax)
    short8 vfb[4];
#pragma unroll
    for (int kk = 0; kk < 2; kk++)
#pragma unroll
      for (int df = 0; df < 2; df++)
        vfb[kk * 2 + df] = *(const short8*)(vrow + (size_t)df * 32 * 2048 + t0 + kk * 16);

    // ---- online softmax (exp2 domain), pair (l, l^32) shares q=l31 ----
    float tmax = fmaxf(fmaxf(vmax16(sacc[0]), vmax16(sacc[1])),
                       fmaxf(vmax16(sacc[2]), vmax16(sacc[3])));
    {
      auto rr = __builtin_amdgcn_permlane32_swap(
          __builtin_bit_cast(unsigned, tmax), __builtin_bit_cast(unsigned, tmax), false, false);
      tmax = fmaxf(__builtin_bit_cast(float, rr[0]), __builtin_bit_cast(float, rr[1]));
    }

    if (!__all(tmax <= mrun + 8.f)) {          // T13 defer-max, THR=8
      float mnew = fmaxf(mrun, tmax);
      float alpha = exp2f(mrun - mnew);
      mrun = mnew;
      lsum *= alpha;
#pragma unroll
      for (int r = 0; r < 16; r++) {
        int rowq = (r & 3) + ((r >> 2) << 3) + (lh << 2);
        float ar = __shfl(alpha, rowq, 64);
        cacc[0][r] *= ar;
        cacc[1][r] *= ar;
      }
    }

    float rsv[4];
#pragma unroll
    for (int tf = 0; tf < 4; tf++) {
      float racc = 0.f;
#pragma unroll
      for (int r = 0; r < 16; r++) {
        float p = exp2f(sacc[tf][r] - mrun);
        sacc[tf][r] = p;
        racc += p;
      }
      rsv[tf] = racc;
    }
    float rs = (rsv[0] + rsv[1]) + (rsv[2] + rsv[3]);
    {
      auto rr = __builtin_amdgcn_permlane32_swap(
          __builtin_bit_cast(unsigned, rs), __builtin_bit_cast(unsigned, rs), false, false);
      rs = __builtin_bit_cast(float, rr[0]) + __builtin_bit_cast(float, rr[1]);
    }
    lsum += rs;

    // ---- PV: per tf, build P A-frags (cvt_pk + permlane32_swap) and accumulate
#pragma unroll
    for (int tf = 0; tf < 4; tf++) {
      short8 pa[2];
#pragma unroll
      for (int kk = 0; kk < 2; kk++) {
        int R = kk * 8;
        unsigned P0 = cvtpk(sacc[tf][R + 0], sacc[tf][R + 1]);
        unsigned P1 = cvtpk(sacc[tf][R + 2], sacc[tf][R + 3]);
        unsigned P2 = cvtpk(sacc[tf][R + 4], sacc[tf][R + 5]);
        unsigned P3 = cvtpk(sacc[tf][R + 6], sacc[tf][R + 7]);
        auto r02 = __builtin_amdgcn_permlane32_swap(P0, P2, false, false);
        auto r13 = __builtin_amdgcn_permlane32_swap(P1, P3, false, false);
        union { unsigned u[4]; short8 s8; } wv;
        wv.u[0] = r02[0];   // {l<32: P0(l),    l>=32: P2(l-32)}  k-local {0,1}
        wv.u[1] = r13[0];   // {l<32: P1(l),    l>=32: P3(l-32)}  k-local {2,3}
        wv.u[2] = r02[1];   // {l<32: P0(l+32), l>=32: P2(l)}     k-local {4,5}
        wv.u[3] = r13[1];   // {l<32: P1(l+32), l>=32: P3(l)}     k-local {6,7}
        pa[kk] = wv.s8;
      }
      // prefetch next tf's V frags
      short8 vfn[4];
      if (tf < 3) {
#pragma unroll
        for (int kk = 0; kk < 2; kk++)
#pragma unroll
          for (int df = 0; df < 2; df++)
            vfn[kk * 2 + df] = *(const short8*)(vrow + (size_t)df * 32 * 2048 + t0 +
                                                (tf + 1) * 32 + kk * 16);
      }
      __builtin_amdgcn_s_setprio(1);
#pragma unroll
      for (int kk = 0; kk < 2; kk++)
#pragma unroll
        for (int df = 0; df < 2; df++)
          cacc[df] = __builtin_amdgcn_mfma_f32_32x32x16_bf16(pa[kk], vfb[kk * 2 + df],
                                                             cacc[df], 0, 0, 0);
      __builtin_amdgcn_s_setprio(0);
      if (tf < 3) {
#pragma unroll
        for (int j = 0; j < 4; j++) vfb[j] = vfn[j];
      }
    }

    __syncthreads();   // drains staged loads + barrier; next K tile ready
    cur ^= 1;
  }
#undef STAGEK

  // epilogue
  float linv = 1.f / lsum;
#pragma unroll
  for (int r = 0; r < 16; r++) {
    int rowq = (r & 3) + ((r >> 2) << 3) + (lh << 2);
    float lr = __shfl(linv, rowq, 64);
    size_t base = (size_t)(b * 2048 + q0 + w * 32 + rowq) * 1024 + h * 64 + l31;
    ctx[base]      = cacc[0][r] * lr;
    ctx[base + 32] = cacc[1][r] * lr;
  }
}

// ---------------- residual + LayerNorm ----------------
__global__ __launch_bounds__(256) void ln_k(const float* __restrict__ ctx,
                                            const float* __restrict__ x,
                                            const float* __restrict__ wgt,
                                            const float* __restrict__ bgam,
                                            float* __restrict__ out) {
  int row = blockIdx.x;
  int tid = threadIdx.x;
  size_t base = (size_t)row * 1024 + tid * 4;
  float4 c = *(const float4*)(ctx + base);
  float4 xv = *(const float4*)(x + base);
  float4 y;
  y.x = c.x + xv.x; y.y = c.y + xv.y; y.z = c.z + xv.z; y.w = c.w + xv.w;
  float s  = y.x + y.y + y.z + y.w;
  float ss = y.x * y.x + y.y * y.y + y.z * y.z + y.w * y.w;
#pragma unroll
  for (int o = 32; o >= 1; o >>= 1) {
    s  += __shfl_xor(s, o, 64);
    ss += __shfl_xor(ss, o, 64);
  }
  __shared__ float sm[8];
  if ((tid & 63) == 0) { sm[(tid >> 6) * 2] = s; sm[(tid >> 6) * 2 + 1] = ss; }
  __syncthreads();
  s  = sm[0] + sm[2] + sm[4] + sm[6];
  ss = sm[1] + sm[3] + sm[5] + sm[7];
  float mu = s * (1.f / 1024.f);
  float var = ss * (1.f / 1024.f) - mu * mu;
  float rstd = rsqrtf(var + 1e-5f);
  float4 wv = *(const float4*)(wgt + tid * 4);
  float4 bv = *(const float4*)(bgam + tid * 4);
  float4 o4;
  o4.x = (y.x - mu) * rstd * wv.x + bv.x;
  o4.y = (y.y - mu) * rstd * wv.y + bv.y;
  o4.z = (y.z - mu) * rstd * wv.z + bv.z;
  o4.w = (y.w - mu) * rstd * wv.w + bv.w;
  *(float4*)(out + base) = o4;
}

// ---------------- launch ----------------
extern "C" void kernel_launch(void* const* d_in, const int* in_sizes, int n_in,
                              void* d_out, int out_size, void* d_ws, size_t ws_size,
                              hipStream_t stream) {
  (void)in_sizes; (void)n_in; (void)out_size; (void)ws_size;
  const float* R  = (const float*)d_in[0];
  const float* En = (const float*)d_in[1];
  const float* x  = (const float*)d_in[2];
  const float* lw = (const float*)d_in[3];
  const float* lb = (const float*)d_in[4];
  float* out = (float*)d_out;

  char* ws = (char*)d_ws;
  unsigned short* xb  = (unsigned short*)(ws);                       // 16 MB bf16 x
  unsigned short* qb  = (unsigned short*)(ws + (size_t)(16u << 20)); // 16 MB Q
  unsigned short* kb  = (unsigned short*)(ws + (size_t)(32u << 20)); // 16 MB K
  unsigned short* vt  = (unsigned short*)(ws + (size_t)(48u << 20)); // 16 MB V^T
  float*          ctx = (float*)(ws + (size_t)(64u << 20));          // 32 MB context
  unsigned short* rt  = (unsigned short*)(ws + (size_t)(96u << 20)); //  2 MB R^T
  unsigned short* et  = (unsigned short*)(ws + (size_t)(98u << 20)); //  2 MB E^T

  prep_wt<<<dim3(16, 16, 2), 256, 0, stream>>>(R, En, rt, et);
  prep_vt<<<dim3(32, 64), 256, 0, stream>>>(x, vt, xb);
  gemm_qk<<<dim3(64, 8), 256, 0, stream>>>(xb, rt, qb, 0.125f * LOG2E);
  gemm_qk<<<dim3(64, 8), 256, 0, stream>>>(xb, et, kb, 1.0f);
  attn_k<<<1024, 256, 0, stream>>>(qb, kb, vt, ctx);
  ln_k<<<8192, 256, 0, stream>>>(ctx, x, lw, lb, out);
}

// Round 4
// 279.716 us; speedup vs baseline: 1.1908x; 1.1908x over previous
//
#include <hip/hip_runtime.h>
#include <hip/hip_bf16.h>

// ---- constants ----
// B=4, S=2048, E=1024, H=16, D=64, scale = 0.125, LN eps 1e-5
#define LOG2E 1.44269504088896340736f

typedef __attribute__((ext_vector_type(8)))  short  short8;
typedef __attribute__((ext_vector_type(4)))  float  f32x4;
typedef __attribute__((ext_vector_type(16))) float  f32x16;

__device__ __forceinline__ unsigned short f2bf(float f) {
  unsigned u = __builtin_bit_cast(unsigned, f);
  return (unsigned short)((u + 0x8000u) >> 16);
}
// pack two fp32 -> bf16x2 in one u32: 2 adds + v_perm_b32 (3 VALU total)
__device__ __forceinline__ unsigned pkbf2(float a, float b) {
  unsigned A = __builtin_bit_cast(unsigned, a) + 0x8000u;
  unsigned B = __builtin_bit_cast(unsigned, b) + 0x8000u;
  return __builtin_amdgcn_perm(B, A, 0x07060302u);  // bytes [B3 B2 A3 A2]
}
// raw v_exp_f32 (exp2): 1 inst, bypasses OCML wrapper
__device__ __forceinline__ float hexp2(float x) {
  float r; asm("v_exp_f32 %0, %1" : "=v"(r) : "v"(x)); return r;
}
__device__ __forceinline__ void gl16(const void* g, void* l) {
  __builtin_amdgcn_global_load_lds(
      (const __attribute__((address_space(1))) void*)g,
      (__attribute__((address_space(3))) void*)l, 16, 0, 0);
}
// tree max of 16
__device__ __forceinline__ float vmax16(f32x16 s) {
  float a[8];
#pragma unroll
  for (int j = 0; j < 8; j++) a[j] = fmaxf(s[2 * j], s[2 * j + 1]);
#pragma unroll
  for (int j = 0; j < 4; j++) a[j] = fmaxf(a[j], a[j + 4]);
  return fmaxf(fmaxf(a[0], a[1]), fmaxf(a[2], a[3]));
}

// ---------------- prep kernels ----------------

// W[e][f] fp32 -> Wt[f][e] bf16 (rotation & entangle; z selects)
__global__ __launch_bounds__(256) void prep_wt(const float* __restrict__ R,
                                               const float* __restrict__ En,
                                               unsigned short* __restrict__ Rt,
                                               unsigned short* __restrict__ Et) {
  const float* src = blockIdx.z ? En : R;
  unsigned short* dst = blockIdx.z ? Et : Rt;
  __shared__ unsigned short t[64][65];
  int e0 = blockIdx.y * 64, f0 = blockIdx.x * 64;
  int tid = threadIdx.x;
  int r = tid >> 2, c4 = (tid & 3) * 16;
#pragma unroll
  for (int j = 0; j < 16; j += 4) {
    float4 v = *(const float4*)(src + (size_t)(e0 + r) * 1024 + f0 + c4 + j);
    t[c4 + j + 0][r] = f2bf(v.x);
    t[c4 + j + 1][r] = f2bf(v.y);
    t[c4 + j + 2][r] = f2bf(v.z);
    t[c4 + j + 3][r] = f2bf(v.w);
  }
  __syncthreads();
  short8 o0, o1;
#pragma unroll
  for (int j = 0; j < 8; j++) {
    o0[j] = (short)t[r][c4 + j];
    o1[j] = (short)t[r][c4 + 8 + j];
  }
  *(short8*)(dst + (size_t)(f0 + r) * 1024 + e0 + c4) = o0;
  *(short8*)(dst + (size_t)(f0 + r) * 1024 + e0 + c4 + 8) = o1;
}

// x -> Vt[(bh*64+d)][s] bf16 AND xb (linear bf16 copy) in one pass
__global__ __launch_bounds__(256) void prep_vt(const float* __restrict__ x,
                                               unsigned short* __restrict__ vt,
                                               unsigned short* __restrict__ xb) {
  int bh = blockIdx.y, b = bh >> 4, h = bh & 15;
  int s0 = blockIdx.x * 64;
  __shared__ unsigned short t[64][65];   // [d][s]
  int tid = threadIdx.x;
  int r = tid >> 2, c4 = (tid & 3) * 16;
#pragma unroll
  for (int j = 0; j < 16; j += 4) {
    float4 v = *(const float4*)(x + (size_t)(b * 2048 + s0 + r) * 1024 + h * 64 + c4 + j);
    ushort4 o;
    o.x = f2bf(v.x); o.y = f2bf(v.y); o.z = f2bf(v.z); o.w = f2bf(v.w);
    t[c4 + j + 0][r] = o.x;
    t[c4 + j + 1][r] = o.y;
    t[c4 + j + 2][r] = o.z;
    t[c4 + j + 3][r] = o.w;
    *(ushort4*)(xb + (size_t)(b * 2048 + s0 + r) * 1024 + h * 64 + c4 + j) = o;
  }
  __syncthreads();
  short8 o0, o1;
#pragma unroll
  for (int j = 0; j < 8; j++) {
    o0[j] = (short)t[r][c4 + j];
    o1[j] = (short)t[r][c4 + 8 + j];
  }
  *(short8*)(vt + (size_t)(bh * 64 + r) * 2048 + s0 + c4) = o0;
  *(short8*)(vt + (size_t)(bh * 64 + r) * 2048 + s0 + c4 + 8) = o1;
}

// ---------------- projection GEMM (m97 structure) ----------------
__global__ __launch_bounds__(256) void gemm_qk(const unsigned short* __restrict__ A,
                                               const unsigned short* __restrict__ Bw,
                                               unsigned short* __restrict__ out,
                                               float scale) {
  int m0 = blockIdx.x * 128, n0 = blockIdx.y * 128;
  int tid = threadIdx.x;
  int w = tid >> 6, l = tid & 63;
  int wr = w >> 1, wc = w & 1;
  int l15 = l & 15, lq = l >> 4;

  __shared__ unsigned short As[128 * 64];
  __shared__ unsigned short Bs[128 * 64];

  f32x4 acc[4][4] = {};

  for (int k0 = 0; k0 < 1024; k0 += 64) {
    __syncthreads();
#pragma unroll
    for (int i = 0; i < 4; i++) {
      int row = i * 32 + (tid >> 3), ch = tid & 7;
      gl16(A  + (size_t)(m0 + row) * 1024 + k0 + ((ch ^ (row & 7)) << 3),
           (char*)As + i * 4096 + w * 1024);
      gl16(Bw + (size_t)(n0 + row) * 1024 + k0 + ((ch ^ (row & 7)) << 3),
           (char*)Bs + i * 4096 + w * 1024);
    }
    __syncthreads();

    short8 af[4][2], bfr[4][2];
#pragma unroll
    for (int mf = 0; mf < 4; mf++)
#pragma unroll
      for (int kk = 0; kk < 2; kk++) {
        int row = wr * 64 + mf * 16 + l15;
        int kb2 = (kk * 32 + lq * 8) * 2;
        af[mf][kk] = *(const short8*)((const char*)As + row * 128 + (kb2 ^ ((row & 7) << 4)));
      }
#pragma unroll
    for (int nf = 0; nf < 4; nf++)
#pragma unroll
      for (int kk = 0; kk < 2; kk++) {
        int row = wc * 64 + nf * 16 + l15;
        int kb2 = (kk * 32 + lq * 8) * 2;
        bfr[nf][kk] = *(const short8*)((const char*)Bs + row * 128 + (kb2 ^ ((row & 7) << 4)));
      }
#pragma unroll
    for (int mf = 0; mf < 4; mf++)
#pragma unroll
      for (int nf = 0; nf < 4; nf++)
#pragma unroll
        for (int kk = 0; kk < 2; kk++)
          acc[mf][nf] = __builtin_amdgcn_mfma_f32_16x16x32_bf16(
              af[mf][kk], bfr[nf][kk], acc[mf][nf], 0, 0, 0);
  }

#pragma unroll
  for (int mf = 0; mf < 4; mf++)
#pragma unroll
    for (int nf = 0; nf < 4; nf++)
#pragma unroll
      for (int r = 0; r < 4; r++) {
        int grow = m0 + wr * 64 + mf * 16 + lq * 4 + r;
        int gcol = n0 + wc * 64 + nf * 16 + l15;
        out[(size_t)grow * 1024 + gcol] = f2bf(acc[mf][nf][r] * scale);
      }
}

// ---------------- flash attention ----------------
// 256 thr = 4 waves, wave owns 32 q-rows, KVBLK=64.
// K and V^T both double-buffered in LDS (2x8KB each = 32KB), 2-phase:
// stage(t+1) -> compute(t) -> __syncthreads (implicit vmcnt drain) -> swap.
// Swapped QK^T (mfma(K,Q)); P-frags via pkbf2 + permlane32_swap.
__global__ __launch_bounds__(256) void attn_k(const unsigned short* __restrict__ Q,
                                              const unsigned short* __restrict__ K,
                                              const unsigned short* __restrict__ VT,
                                              float* __restrict__ ctx) {
  int f = blockIdx.x;
  int bh = ((f >> 7) << 3) | (f & 7);   // cluster a head's q-tiles on one XCD
  int qt = (f >> 3) & 15;
  int b = bh >> 4, h = bh & 15;
  int q0 = qt * 128;
  int tid = threadIdx.x;
  int w = tid >> 6, l = tid & 63;
  int lh = l >> 5, l31 = l & 31;

  __shared__ unsigned short Kl[2 * 64 * 64];   // [buf][t'][d], swizzled, 16KB
  __shared__ unsigned short Vl[2 * 64 * 64];   // [buf][d][t'], swizzled, 16KB

  // Q fragments (B-operand): lane holds Q[q=l31][d = dk*16 + lh*8 + j]
  int qrow = q0 + w * 32 + l31;
  const unsigned short* qp = Q + (size_t)(b * 2048 + qrow) * 1024 + h * 64;
  short8 qf[4];
#pragma unroll
  for (int dk = 0; dk < 4; dk++) qf[dk] = *(const short8*)(qp + dk * 16 + lh * 8);

  f32x16 cacc[2] = {};
  float mrun = -INFINITY, lsum = 0.f;

  // stage K[64][64] + V^T[64][64] for tile at t'=tt into buffer `buf`
#define STAGE(buf, tt)                                                        \
  {                                                                           \
    _Pragma("unroll") for (int i_ = 0; i_ < 2; i_++) {                        \
      int row_ = i_ * 32 + (tid >> 3), ch_ = tid & 7;                         \
      gl16(K + (size_t)(b * 2048 + (tt) + row_) * 1024 + h * 64 +             \
               ((ch_ ^ (row_ & 7)) << 3),                                     \
           (char*)Kl + (buf) * 8192 + i_ * 4096 + w * 1024);                  \
      gl16(VT + (size_t)(bh * 64 + row_) * 2048 + (tt) +                      \
               ((ch_ ^ (row_ & 7)) << 3),                                     \
           (char*)Vl + (buf) * 8192 + i_ * 4096 + w * 1024);                  \
    }                                                                         \
  }

  STAGE(0, 0);
  __syncthreads();
  int cur = 0;

  for (int tc = 0; tc < 32; tc++) {
    int t0 = tc * 64;
    if (tc < 31) STAGE(cur ^ 1, t0 + 64);

    const char* Kb = (const char*)Kl + cur * 8192;
    const char* Vb = (const char*)Vl + cur * 8192;

    // ---- QK^T: S^T[t'][q], t' in [t0, t0+64) ----
    f32x16 sacc[2] = {};
    __builtin_amdgcn_s_setprio(1);
#pragma unroll
    for (int tf = 0; tf < 2; tf++) {
#pragma unroll
      for (int dk = 0; dk < 4; dk++) {
        int row = tf * 32 + l31;
        int kb2 = (dk * 16 + lh * 8) * 2;
        short8 kf = *(const short8*)(Kb + row * 128 + (kb2 ^ ((row & 7) << 4)));
        sacc[tf] = __builtin_amdgcn_mfma_f32_32x32x16_bf16(kf, qf[dk], sacc[tf], 0, 0, 0);
      }
    }
    __builtin_amdgcn_s_setprio(0);

    // ---- online softmax (exp2 domain), pair (l, l^32) shares q=l31 ----
    float tmax = fmaxf(vmax16(sacc[0]), vmax16(sacc[1]));
    {
      auto rr = __builtin_amdgcn_permlane32_swap(
          __builtin_bit_cast(unsigned, tmax), __builtin_bit_cast(unsigned, tmax), false, false);
      tmax = fmaxf(__builtin_bit_cast(float, rr[0]), __builtin_bit_cast(float, rr[1]));
    }

    if (!__all(tmax <= mrun + 8.f)) {          // T13 defer-max, THR=8
      float mnew = fmaxf(mrun, tmax);
      float alpha = hexp2(mrun - mnew);
      mrun = mnew;
      lsum *= alpha;
#pragma unroll
      for (int r = 0; r < 16; r++) {
        int rowq = (r & 3) + ((r >> 2) << 3) + (lh << 2);
        float ar = __shfl(alpha, rowq, 64);
        cacc[0][r] *= ar;
        cacc[1][r] *= ar;
      }
    }

    float racc0 = 0.f, racc1 = 0.f;
#pragma unroll
    for (int r = 0; r < 16; r++) {
      float p0 = hexp2(sacc[0][r] - mrun);
      float p1 = hexp2(sacc[1][r] - mrun);
      sacc[0][r] = p0;
      sacc[1][r] = p1;
      racc0 += p0;
      racc1 += p1;
    }
    float rs = racc0 + racc1;
    {
      auto rr = __builtin_amdgcn_permlane32_swap(
          __builtin_bit_cast(unsigned, rs), __builtin_bit_cast(unsigned, rs), false, false);
      rs = __builtin_bit_cast(float, rr[0]) + __builtin_bit_cast(float, rr[1]);
    }
    lsum += rs;

    // ---- PV: per tf, build P A-frags (pkbf2 + permlane32_swap) and accumulate
#pragma unroll
    for (int tf = 0; tf < 2; tf++) {
      short8 pa[2];
#pragma unroll
      for (int kk = 0; kk < 2; kk++) {
        int R = kk * 8;
        unsigned P0 = pkbf2(sacc[tf][R + 0], sacc[tf][R + 1]);
        unsigned P1 = pkbf2(sacc[tf][R + 2], sacc[tf][R + 3]);
        unsigned P2 = pkbf2(sacc[tf][R + 4], sacc[tf][R + 5]);
        unsigned P3 = pkbf2(sacc[tf][R + 6], sacc[tf][R + 7]);
        auto r02 = __builtin_amdgcn_permlane32_swap(P0, P2, false, false);
        auto r13 = __builtin_amdgcn_permlane32_swap(P1, P3, false, false);
        union { unsigned u[4]; short8 s8; } wv;
        wv.u[0] = r02[0];   // k-local {0,1}
        wv.u[1] = r13[0];   // k-local {2,3}
        wv.u[2] = r02[1];   // k-local {4,5}
        wv.u[3] = r13[1];   // k-local {6,7}
        pa[kk] = wv.s8;
      }
      __builtin_amdgcn_s_setprio(1);
#pragma unroll
      for (int kk = 0; kk < 2; kk++)
#pragma unroll
        for (int df = 0; df < 2; df++) {
          int drow = df * 32 + l31;
          int tb2 = (tf * 32 + kk * 16 + lh * 8) * 2;
          short8 vf = *(const short8*)(Vb + drow * 128 + (tb2 ^ ((l31 & 7) << 4)));
          cacc[df] = __builtin_amdgcn_mfma_f32_32x32x16_bf16(pa[kk], vf, cacc[df], 0, 0, 0);
        }
      __builtin_amdgcn_s_setprio(0);
    }

    __syncthreads();   // drains stage(t+1) loads + barrier; swap buffers
    cur ^= 1;
  }
#undef STAGE

  // epilogue
  float linv = 1.f / lsum;
#pragma unroll
  for (int r = 0; r < 16; r++) {
    int rowq = (r & 3) + ((r >> 2) << 3) + (lh << 2);
    float lr = __shfl(linv, rowq, 64);
    size_t base = (size_t)(b * 2048 + q0 + w * 32 + rowq) * 1024 + h * 64 + l31;
    ctx[base]      = cacc[0][r] * lr;
    ctx[base + 32] = cacc[1][r] * lr;
  }
}

// ---------------- residual + LayerNorm ----------------
__global__ __launch_bounds__(256) void ln_k(const float* __restrict__ ctx,
                                            const float* __restrict__ x,
                                            const float* __restrict__ wgt,
                                            const float* __restrict__ bgam,
                                            float* __restrict__ out) {
  int row = blockIdx.x;
  int tid = threadIdx.x;
  size_t base = (size_t)row * 1024 + tid * 4;
  float4 c = *(const float4*)(ctx + base);
  float4 xv = *(const float4*)(x + base);
  float4 y;
  y.x = c.x + xv.x; y.y = c.y + xv.y; y.z = c.z + xv.z; y.w = c.w + xv.w;
  float s  = y.x + y.y + y.z + y.w;
  float ss = y.x * y.x + y.y * y.y + y.z * y.z + y.w * y.w;
#pragma unroll
  for (int o = 32; o >= 1; o >>= 1) {
    s  += __shfl_xor(s, o, 64);
    ss += __shfl_xor(ss, o, 64);
  }
  __shared__ float sm[8];
  if ((tid & 63) == 0) { sm[(tid >> 6) * 2] = s; sm[(tid >> 6) * 2 + 1] = ss; }
  __syncthreads();
  s  = sm[0] + sm[2] + sm[4] + sm[6];
  ss = sm[1] + sm[3] + sm[5] + sm[7];
  float mu = s * (1.f / 1024.f);
  float var = ss * (1.f / 1024.f) - mu * mu;
  float rstd = rsqrtf(var + 1e-5f);
  float4 wv = *(const float4*)(wgt + tid * 4);
  float4 bv = *(const float4*)(bgam + tid * 4);
  float4 o4;
  o4.x = (y.x - mu) * rstd * wv.x + bv.x;
  o4.y = (y.y - mu) * rstd * wv.y + bv.y;
  o4.z = (y.z - mu) * rstd * wv.z + bv.z;
  o4.w = (y.w - mu) * rstd * wv.w + bv.w;
  *(float4*)(out + base) = o4;
}

// ---------------- launch ----------------
extern "C" void kernel_launch(void* const* d_in, const int* in_sizes, int n_in,
                              void* d_out, int out_size, void* d_ws, size_t ws_size,
                              hipStream_t stream) {
  (void)in_sizes; (void)n_in; (void)out_size; (void)ws_size;
  const float* R  = (const float*)d_in[0];
  const float* En = (const float*)d_in[1];
  const float* x  = (const float*)d_in[2];
  const float* lw = (const float*)d_in[3];
  const float* lb = (const float*)d_in[4];
  float* out = (float*)d_out;

  char* ws = (char*)d_ws;
  unsigned short* xb  = (unsigned short*)(ws);                       // 16 MB bf16 x
  unsigned short* qb  = (unsigned short*)(ws + (size_t)(16u << 20)); // 16 MB Q
  unsigned short* kb  = (unsigned short*)(ws + (size_t)(32u << 20)); // 16 MB K
  unsigned short* vt  = (unsigned short*)(ws + (size_t)(48u << 20)); // 16 MB V^T
  float*          ctx = (float*)(ws + (size_t)(64u << 20));          // 32 MB context
  unsigned short* rt  = (unsigned short*)(ws + (size_t)(96u << 20)); //  2 MB R^T
  unsigned short* et  = (unsigned short*)(ws + (size_t)(98u << 20)); //  2 MB E^T

  prep_wt<<<dim3(16, 16, 2), 256, 0, stream>>>(R, En, rt, et);
  prep_vt<<<dim3(32, 64), 256, 0, stream>>>(x, vt, xb);
  gemm_qk<<<dim3(64, 8), 256, 0, stream>>>(xb, rt, qb, 0.125f * LOG2E);
  gemm_qk<<<dim3(64, 8), 256, 0, stream>>>(xb, et, kb, 1.0f);
  attn_k<<<1024, 256, 0, stream>>>(qb, kb, vt, ctx);
  ln_k<<<8192, 256, 0, stream>>>(ctx, x, lw, lb, out);
}

// Round 5
// 251.481 us; speedup vs baseline: 1.3245x; 1.1123x over previous
//
#include <hip/hip_runtime.h>
#include <hip/hip_bf16.h>

// ---- constants ----
// B=4, S=2048, E=1024, H=16, D=64, scale = 0.125, LN eps 1e-5
#define LOG2E 1.44269504088896340736f

typedef __attribute__((ext_vector_type(8)))  short  short8;
typedef __attribute__((ext_vector_type(2)))  float  f32x2;
typedef __attribute__((ext_vector_type(4)))  float  f32x4;
typedef __attribute__((ext_vector_type(16))) float  f32x16;

__device__ __forceinline__ unsigned short f2bf(float f) {
  unsigned u = __builtin_bit_cast(unsigned, f);
  return (unsigned short)((u + 0x8000u) >> 16);
}
__device__ __forceinline__ float bf2f(unsigned short u) {
  return __builtin_bit_cast(float, (unsigned)u << 16);
}
// packed f32 add (VOP3P), 2 elems / inst
__device__ __forceinline__ f32x2 pkadd(f32x2 a, f32x2 b) {
  f32x2 r; asm("v_pk_add_f32 %0, %1, %2" : "=v"(r) : "v"(a), "v"(b)); return r;
}
// 2×f32 -> packed bf16x2, 1 inst (lo = a, hi = b)
__device__ __forceinline__ unsigned cvtpk2(float a, float b) {
  unsigned r; asm("v_cvt_pk_bf16_f32 %0, %1, %2" : "=v"(r) : "v"(a), "v"(b)); return r;
}
// raw v_exp_f32 (exp2)
__device__ __forceinline__ float hexp2(float x) {
  float r; asm("v_exp_f32 %0, %1" : "=v"(r) : "v"(x)); return r;
}
__device__ __forceinline__ float m3(float a, float b, float c) {
  return fmaxf(fmaxf(a, b), c);   // clang fuses to v_max3_f32
}
__device__ __forceinline__ void gl16(const void* g, void* l) {
  __builtin_amdgcn_global_load_lds(
      (const __attribute__((address_space(1))) void*)g,
      (__attribute__((address_space(3))) void*)l, 16, 0, 0);
}

// ---------------- prep kernels ----------------

// W[e][f] fp32 -> Wt[f][e] bf16 (rotation & entangle; z selects; outputs contiguous)
__global__ __launch_bounds__(256) void prep_wt(const float* __restrict__ R,
                                               const float* __restrict__ En,
                                               unsigned short* __restrict__ Rt,
                                               unsigned short* __restrict__ Et) {
  const float* src = blockIdx.z ? En : R;
  unsigned short* dst = blockIdx.z ? Et : Rt;
  __shared__ unsigned short t[64][65];
  int e0 = blockIdx.y * 64, f0 = blockIdx.x * 64;
  int tid = threadIdx.x;
  int r = tid >> 2, c4 = (tid & 3) * 16;
#pragma unroll
  for (int j = 0; j < 16; j += 4) {
    float4 v = *(const float4*)(src + (size_t)(e0 + r) * 1024 + f0 + c4 + j);
    t[c4 + j + 0][r] = f2bf(v.x);
    t[c4 + j + 1][r] = f2bf(v.y);
    t[c4 + j + 2][r] = f2bf(v.z);
    t[c4 + j + 3][r] = f2bf(v.w);
  }
  __syncthreads();
  short8 o0, o1;
#pragma unroll
  for (int j = 0; j < 8; j++) {
    o0[j] = (short)t[r][c4 + j];
    o1[j] = (short)t[r][c4 + 8 + j];
  }
  *(short8*)(dst + (size_t)(f0 + r) * 1024 + e0 + c4) = o0;
  *(short8*)(dst + (size_t)(f0 + r) * 1024 + e0 + c4 + 8) = o1;
}

// x -> Vt[(bh*64+d)][s] bf16 AND xb (linear bf16) in one pass
__global__ __launch_bounds__(256) void prep_vt(const float* __restrict__ x,
                                               unsigned short* __restrict__ vt,
                                               unsigned short* __restrict__ xb) {
  int bh = blockIdx.y, b = bh >> 4, h = bh & 15;
  int s0 = blockIdx.x * 64;
  __shared__ unsigned short t[64][65];   // [d][s]
  int tid = threadIdx.x;
  int r = tid >> 2, c4 = (tid & 3) * 16;
#pragma unroll
  for (int j = 0; j < 16; j += 4) {
    float4 v = *(const float4*)(x + (size_t)(b * 2048 + s0 + r) * 1024 + h * 64 + c4 + j);
    ushort4 o;
    o.x = f2bf(v.x); o.y = f2bf(v.y); o.z = f2bf(v.z); o.w = f2bf(v.w);
    t[c4 + j + 0][r] = o.x;
    t[c4 + j + 1][r] = o.y;
    t[c4 + j + 2][r] = o.z;
    t[c4 + j + 3][r] = o.w;
    *(ushort4*)(xb + (size_t)(b * 2048 + s0 + r) * 1024 + h * 64 + c4 + j) = o;
  }
  __syncthreads();
  short8 o0, o1;
#pragma unroll
  for (int j = 0; j < 8; j++) {
    o0[j] = (short)t[r][c4 + j];
    o1[j] = (short)t[r][c4 + 8 + j];
  }
  *(short8*)(vt + (size_t)(bh * 64 + r) * 2048 + s0 + c4) = o0;
  *(short8*)(vt + (size_t)(bh * 64 + r) * 2048 + s0 + c4 + 8) = o1;
}

// ------------- fused projection GEMM: [Q|K] = xb · [Rt|Et]^T -------------
// Bw = rt base; rows 0..1023 = Rt (Q), 1024..2047 = Et (K), contiguous.
// 128x128 tile, BK=64, 4 waves 2x2, 16x16x32 MFMA, m97 structure.
__global__ __launch_bounds__(256) void gemm_qk2(const unsigned short* __restrict__ A,
                                                const unsigned short* __restrict__ Bw,
                                                unsigned short* __restrict__ qb,
                                                unsigned short* __restrict__ kb,
                                                float qs) {
  int m0 = blockIdx.x * 128, n0 = blockIdx.y * 128;
  int tid = threadIdx.x;
  int w = tid >> 6, l = tid & 63;
  int wr = w >> 1, wc = w & 1;
  int l15 = l & 15, lq = l >> 4;

  __shared__ unsigned short As[128 * 64];
  __shared__ unsigned short Bs[128 * 64];

  f32x4 acc[4][4] = {};

  for (int k0 = 0; k0 < 1024; k0 += 64) {
    __syncthreads();
#pragma unroll
    for (int i = 0; i < 4; i++) {
      int row = i * 32 + (tid >> 3), ch = tid & 7;
      gl16(A  + (size_t)(m0 + row) * 1024 + k0 + ((ch ^ (row & 7)) << 3),
           (char*)As + i * 4096 + w * 1024);
      gl16(Bw + (size_t)(n0 + row) * 1024 + k0 + ((ch ^ (row & 7)) << 3),
           (char*)Bs + i * 4096 + w * 1024);
    }
    __syncthreads();

    short8 af[4][2], bfr[4][2];
#pragma unroll
    for (int mf = 0; mf < 4; mf++)
#pragma unroll
      for (int kk = 0; kk < 2; kk++) {
        int row = wr * 64 + mf * 16 + l15;
        int kb2 = (kk * 32 + lq * 8) * 2;
        af[mf][kk] = *(const short8*)((const char*)As + row * 128 + (kb2 ^ ((row & 7) << 4)));
      }
#pragma unroll
    for (int nf = 0; nf < 4; nf++)
#pragma unroll
      for (int kk = 0; kk < 2; kk++) {
        int row = wc * 64 + nf * 16 + l15;
        int kb2 = (kk * 32 + lq * 8) * 2;
        bfr[nf][kk] = *(const short8*)((const char*)Bs + row * 128 + (kb2 ^ ((row & 7) << 4)));
      }
#pragma unroll
    for (int mf = 0; mf < 4; mf++)
#pragma unroll
      for (int nf = 0; nf < 4; nf++)
#pragma unroll
        for (int kk = 0; kk < 2; kk++)
          acc[mf][nf] = __builtin_amdgcn_mfma_f32_16x16x32_bf16(
              af[mf][kk], bfr[nf][kk], acc[mf][nf], 0, 0, 0);
  }

  unsigned short* out = (n0 < 1024) ? qb : kb;
  float scale = (n0 < 1024) ? qs : 1.0f;
  int cb = n0 & 1023;
#pragma unroll
  for (int mf = 0; mf < 4; mf++)
#pragma unroll
    for (int nf = 0; nf < 4; nf++)
#pragma unroll
      for (int r = 0; r < 4; r++) {
        int grow = m0 + wr * 64 + mf * 16 + lq * 4 + r;
        int gcol = cb + wc * 64 + nf * 16 + l15;
        out[(size_t)grow * 1024 + gcol] = f2bf(acc[mf][nf][r] * scale);
      }
}

// ---------------- flash attention ----------------
// 256 thr = 4 waves, wave owns 32 q-rows, KVBLK=64, K+V double-buffered (32KB).
// 2x unrolled tile loop -> buffer parity compile-time; all LDS read addresses
// precomputed per lane (loop-invariant), tf/df/buf are ds offset immediates.
__global__ __launch_bounds__(256, 4) void attn_k(const unsigned short* __restrict__ Q,
                                                 const unsigned short* __restrict__ K,
                                                 const unsigned short* __restrict__ VT,
                                                 unsigned short* __restrict__ ctx) {
  int f = blockIdx.x;
  int bh = ((f >> 7) << 3) | (f & 7);   // cluster a head's q-tiles on one XCD
  int qt = (f >> 3) & 15;
  int b = bh >> 4, h = bh & 15;
  int q0 = qt * 128;
  int tid = threadIdx.x;
  int w = tid >> 6, l = tid & 63;
  int lh = l >> 5, l31 = l & 31;

  __shared__ unsigned short Kl[2 * 64 * 64];   // [buf][t'][d], swizzled
  __shared__ unsigned short Vl[2 * 64 * 64];   // [buf][d][t'], swizzled

  // Q fragments (B-operand): lane holds Q[q=l31][d = dk*16 + lh*8 + j]
  int qrow = q0 + w * 32 + l31;
  const unsigned short* qp = Q + (size_t)(b * 2048 + qrow) * 1024 + h * 64;
  short8 qf[4];
#pragma unroll
  for (int dk = 0; dk < 4; dk++) qf[dk] = *(const short8*)(qp + dk * 16 + lh * 8);

  // precomputed lane-invariant LDS byte offsets (swizzle key fixed per lane)
  int key = (l31 & 7) << 4;
  int koff[4], voff[4];
#pragma unroll
  for (int dk = 0; dk < 4; dk++) koff[dk] = l31 * 128 + ((dk * 32 + lh * 16) ^ key);
#pragma unroll
  for (int tf = 0; tf < 2; tf++)
#pragma unroll
    for (int kk = 0; kk < 2; kk++)
      voff[tf * 2 + kk] = l31 * 128 + ((tf * 64 + kk * 32 + lh * 16) ^ key);

  const char* KB = (const char*)Kl;
  const char* VB = (const char*)Vl;

  f32x16 cacc[2] = {};
  float mrun = -INFINITY, lsl = 0.f;

#define STAGE(buf, tt)                                                        \
  {                                                                           \
    _Pragma("unroll") for (int i_ = 0; i_ < 2; i_++) {                        \
      int row_ = i_ * 32 + (tid >> 3), ch_ = tid & 7;                         \
      gl16(K + (size_t)(b * 2048 + (tt) + row_) * 1024 + h * 64 +             \
               ((ch_ ^ (row_ & 7)) << 3),                                     \
           (char*)Kl + (buf) * 8192 + i_ * 4096 + w * 1024);                  \
      gl16(VT + (size_t)(bh * 64 + row_) * 2048 + (tt) +                      \
               ((ch_ ^ (row_ & 7)) << 3),                                     \
           (char*)Vl + (buf) * 8192 + i_ * 4096 + w * 1024);                  \
    }                                                                         \
  }

#define COMPUTE(IMM)                                                          \
  do {                                                                        \
    f32x16 sacc[2] = {};                                                      \
    __builtin_amdgcn_s_setprio(1);                                            \
    _Pragma("unroll") for (int tf = 0; tf < 2; tf++)                          \
      _Pragma("unroll") for (int dk = 0; dk < 4; dk++) {                      \
        short8 kf = *(const short8*)(KB + koff[dk] + (IMM) + tf * 4096);      \
        sacc[tf] = __builtin_amdgcn_mfma_f32_32x32x16_bf16(kf, qf[dk],        \
                                                           sacc[tf], 0, 0, 0);\
      }                                                                       \
    __builtin_amdgcn_s_setprio(0);                                            \
    float t16[16];                                                            \
    _Pragma("unroll") for (int j = 0; j < 16; j++)                            \
      t16[j] = fmaxf(sacc[0][j], sacc[1][j]);                                 \
    float t8[8];                                                              \
    _Pragma("unroll") for (int j = 0; j < 8; j++)                             \
      t8[j] = fmaxf(t16[j], t16[j + 8]);                                      \
    float lmax = m3(m3(t8[0], t8[1], t8[2]), m3(t8[3], t8[4], t8[5]),         \
                    fmaxf(t8[6], t8[7]));                                     \
    if (!__all(lmax <= mrun + 8.f)) {                                         \
      unsigned lu = __builtin_bit_cast(unsigned, lmax);                       \
      auto rr = __builtin_amdgcn_permlane32_swap(lu, lu, false, false);       \
      float pm = fmaxf(__builtin_bit_cast(float, rr[0]),                      \
                       __builtin_bit_cast(float, rr[1]));                     \
      float mnew = fmaxf(mrun, pm);                                           \
      float alpha = hexp2(mrun - mnew);                                       \
      mrun = mnew; lsl *= alpha;                                              \
      _Pragma("unroll") for (int r = 0; r < 16; r++) {                        \
        int rowq = (r & 3) + ((r >> 2) << 3) + (lh << 2);                     \
        float ar = __shfl(alpha, rowq, 64);                                   \
        cacc[0][r] *= ar; cacc[1][r] *= ar;                                   \
      }                                                                       \
    }                                                                         \
    f32x2 negm2; negm2[0] = -mrun; negm2[1] = -mrun;                          \
    f32x2 r2; r2[0] = 0.f; r2[1] = 0.f;                                       \
    _Pragma("unroll") for (int tf = 0; tf < 2; tf++) {                        \
      unsigned pw[8];                                                         \
      _Pragma("unroll") for (int j = 0; j < 8; j++) {                         \
        f32x2 s2; s2[0] = sacc[tf][2 * j]; s2[1] = sacc[tf][2 * j + 1];       \
        f32x2 d = pkadd(s2, negm2);                                           \
        float e0 = hexp2(d[0]), e1 = hexp2(d[1]);                             \
        f32x2 e2; e2[0] = e0; e2[1] = e1;                                     \
        r2 = pkadd(r2, e2);                                                   \
        pw[j] = cvtpk2(e0, e1);                                               \
      }                                                                       \
      short8 pa[2];                                                           \
      _Pragma("unroll") for (int kk = 0; kk < 2; kk++) {                      \
        auto r02 = __builtin_amdgcn_permlane32_swap(pw[kk * 4 + 0],           \
                                                    pw[kk * 4 + 2], false, false); \
        auto r13 = __builtin_amdgcn_permlane32_swap(pw[kk * 4 + 1],           \
                                                    pw[kk * 4 + 3], false, false); \
        union { unsigned u[4]; short8 s8; } wv;                               \
        wv.u[0] = r02[0]; wv.u[1] = r13[0];                                   \
        wv.u[2] = r02[1]; wv.u[3] = r13[1];                                   \
        pa[kk] = wv.s8;                                                       \
      }                                                                       \
      __builtin_amdgcn_s_setprio(1);                                          \
      _Pragma("unroll") for (int kk = 0; kk < 2; kk++)                        \
        _Pragma("unroll") for (int df = 0; df < 2; df++) {                    \
          short8 vf = *(const short8*)(VB + voff[tf * 2 + kk] + (IMM) +       \
                                       df * 4096);                            \
          cacc[df] = __builtin_amdgcn_mfma_f32_32x32x16_bf16(pa[kk], vf,      \
                                                             cacc[df], 0, 0, 0); \
        }                                                                     \
      __builtin_amdgcn_s_setprio(0);                                          \
    }                                                                         \
    lsl += r2[0] + r2[1];                                                     \
  } while (0)

  STAGE(0, 0);
  __syncthreads();

  for (int tc2 = 0; tc2 < 16; tc2++) {
    int t0 = tc2 * 128;
    STAGE(1, t0 + 64);          // always valid (t0+64 <= 1984)
    COMPUTE(0);
    __syncthreads();
    if (tc2 < 15) STAGE(0, t0 + 128);
    COMPUTE(8192);
    __syncthreads();
  }
#undef STAGE
#undef COMPUTE

  // epilogue: combine pair sums, normalize, store bf16
  {
    unsigned lu = __builtin_bit_cast(unsigned, lsl);
    auto rr = __builtin_amdgcn_permlane32_swap(lu, lu, false, false);
    lsl = __builtin_bit_cast(float, rr[0]) + __builtin_bit_cast(float, rr[1]);
  }
  float linv = 1.f / lsl;
#pragma unroll
  for (int r = 0; r < 16; r++) {
    int rowq = (r & 3) + ((r >> 2) << 3) + (lh << 2);
    float lr = __shfl(linv, rowq, 64);
    size_t base = (size_t)(b * 2048 + q0 + w * 32 + rowq) * 1024 + h * 64 + l31;
    ctx[base]      = f2bf(cacc[0][r] * lr);
    ctx[base + 32] = f2bf(cacc[1][r] * lr);
  }
}

// ---------------- residual + LayerNorm (bf16 ctx input) ----------------
__global__ __launch_bounds__(256) void ln_k(const unsigned short* __restrict__ ctx,
                                            const float* __restrict__ x,
                                            const float* __restrict__ wgt,
                                            const float* __restrict__ bgam,
                                            float* __restrict__ out) {
  int row = blockIdx.x;
  int tid = threadIdx.x;
  size_t base = (size_t)row * 1024 + tid * 4;
  ushort4 cu = *(const ushort4*)(ctx + base);
  float4 xv = *(const float4*)(x + base);
  float4 y;
  y.x = bf2f(cu.x) + xv.x; y.y = bf2f(cu.y) + xv.y;
  y.z = bf2f(cu.z) + xv.z; y.w = bf2f(cu.w) + xv.w;
  float s  = y.x + y.y + y.z + y.w;
  float ss = y.x * y.x + y.y * y.y + y.z * y.z + y.w * y.w;
#pragma unroll
  for (int o = 32; o >= 1; o >>= 1) {
    s  += __shfl_xor(s, o, 64);
    ss += __shfl_xor(ss, o, 64);
  }
  __shared__ float sm[8];
  if ((tid & 63) == 0) { sm[(tid >> 6) * 2] = s; sm[(tid >> 6) * 2 + 1] = ss; }
  __syncthreads();
  s  = sm[0] + sm[2] + sm[4] + sm[6];
  ss = sm[1] + sm[3] + sm[5] + sm[7];
  float mu = s * (1.f / 1024.f);
  float var = ss * (1.f / 1024.f) - mu * mu;
  float rstd = rsqrtf(var + 1e-5f);
  float4 wv = *(const float4*)(wgt + tid * 4);
  float4 bv = *(const float4*)(bgam + tid * 4);
  float4 o4;
  o4.x = (y.x - mu) * rstd * wv.x + bv.x;
  o4.y = (y.y - mu) * rstd * wv.y + bv.y;
  o4.z = (y.z - mu) * rstd * wv.z + bv.z;
  o4.w = (y.w - mu) * rstd * wv.w + bv.w;
  *(float4*)(out + base) = o4;
}

// ---------------- launch ----------------
extern "C" void kernel_launch(void* const* d_in, const int* in_sizes, int n_in,
                              void* d_out, int out_size, void* d_ws, size_t ws_size,
                              hipStream_t stream) {
  (void)in_sizes; (void)n_in; (void)out_size; (void)ws_size;
  const float* R  = (const float*)d_in[0];
  const float* En = (const float*)d_in[1];
  const float* x  = (const float*)d_in[2];
  const float* lw = (const float*)d_in[3];
  const float* lb = (const float*)d_in[4];
  float* out = (float*)d_out;

  char* ws = (char*)d_ws;
  unsigned short* xb  = (unsigned short*)(ws);                       // 16 MB bf16 x
  unsigned short* qb  = (unsigned short*)(ws + (size_t)(16u << 20)); // 16 MB Q
  unsigned short* kb  = (unsigned short*)(ws + (size_t)(32u << 20)); // 16 MB K
  unsigned short* vt  = (unsigned short*)(ws + (size_t)(48u << 20)); // 16 MB V^T
  unsigned short* ctx = (unsigned short*)(ws + (size_t)(64u << 20)); // 16 MB context bf16
  unsigned short* rt  = (unsigned short*)(ws + (size_t)(96u << 20)); // 2 MB R^T
  unsigned short* et  = (unsigned short*)(ws + (size_t)(98u << 20)); // 2 MB E^T (contiguous after rt)

  prep_wt<<<dim3(16, 16, 2), 256, 0, stream>>>(R, En, rt, et);
  prep_vt<<<dim3(32, 64), 256, 0, stream>>>(x, vt, xb);
  gemm_qk2<<<dim3(64, 16), 256, 0, stream>>>(xb, rt, qb, kb, 0.125f * LOG2E);
  attn_k<<<1024, 256, 0, stream>>>(qb, kb, vt, ctx);
  ln_k<<<8192, 256, 0, stream>>>(ctx, x, lw, lb, out);
}

// Round 6
// 248.424 us; speedup vs baseline: 1.3408x; 1.0123x over previous
//
#include <hip/hip_runtime.h>
#include <hip/hip_bf16.h>

// ---- constants ----
// B=4, S=2048, E=1024, H=16, D=64, scale = 0.125, LN eps 1e-5
#define LOG2E 1.44269504088896340736f

typedef __attribute__((ext_vector_type(8)))  short  short8;
typedef __attribute__((ext_vector_type(2)))  float  f32x2;
typedef __attribute__((ext_vector_type(4)))  float  f32x4;
typedef __attribute__((ext_vector_type(16))) float  f32x16;

__device__ __forceinline__ unsigned short f2bf(float f) {
  unsigned u = __builtin_bit_cast(unsigned, f);
  return (unsigned short)((u + 0x8000u) >> 16);
}
__device__ __forceinline__ float bf2f(unsigned short u) {
  return __builtin_bit_cast(float, (unsigned)u << 16);
}
// packed f32 add (VOP3P), 2 elems / inst
__device__ __forceinline__ f32x2 pkadd(f32x2 a, f32x2 b) {
  f32x2 r; asm("v_pk_add_f32 %0, %1, %2" : "=v"(r) : "v"(a), "v"(b)); return r;
}
// 2×f32 -> packed bf16x2, 1 inst (lo = a, hi = b)
__device__ __forceinline__ unsigned cvtpk2(float a, float b) {
  unsigned r; asm("v_cvt_pk_bf16_f32 %0, %1, %2" : "=v"(r) : "v"(a), "v"(b)); return r;
}
// raw v_exp_f32 (exp2)
__device__ __forceinline__ float hexp2(float x) {
  float r; asm("v_exp_f32 %0, %1" : "=v"(r) : "v"(x)); return r;
}
__device__ __forceinline__ float m3(float a, float b, float c) {
  return fmaxf(fmaxf(a, b), c);   // clang fuses to v_max3_f32
}
__device__ __forceinline__ void gl16(const void* g, void* l) {
  __builtin_amdgcn_global_load_lds(
      (const __attribute__((address_space(1))) void*)g,
      (__attribute__((address_space(3))) void*)l, 16, 0, 0);
}

// ---------------- prep kernels ----------------

// W[e][f] fp32 -> Wt[f][e] bf16 (rotation & entangle; z selects; outputs contiguous)
__global__ __launch_bounds__(256) void prep_wt(const float* __restrict__ R,
                                               const float* __restrict__ En,
                                               unsigned short* __restrict__ Rt,
                                               unsigned short* __restrict__ Et) {
  const float* src = blockIdx.z ? En : R;
  unsigned short* dst = blockIdx.z ? Et : Rt;
  __shared__ unsigned short t[64][65];
  int e0 = blockIdx.y * 64, f0 = blockIdx.x * 64;
  int tid = threadIdx.x;
  int r = tid >> 2, c4 = (tid & 3) * 16;
#pragma unroll
  for (int j = 0; j < 16; j += 4) {
    float4 v = *(const float4*)(src + (size_t)(e0 + r) * 1024 + f0 + c4 + j);
    t[c4 + j + 0][r] = f2bf(v.x);
    t[c4 + j + 1][r] = f2bf(v.y);
    t[c4 + j + 2][r] = f2bf(v.z);
    t[c4 + j + 3][r] = f2bf(v.w);
  }
  __syncthreads();
  short8 o0, o1;
#pragma unroll
  for (int j = 0; j < 8; j++) {
    o0[j] = (short)t[r][c4 + j];
    o1[j] = (short)t[r][c4 + 8 + j];
  }
  *(short8*)(dst + (size_t)(f0 + r) * 1024 + e0 + c4) = o0;
  *(short8*)(dst + (size_t)(f0 + r) * 1024 + e0 + c4 + 8) = o1;
}

// x -> Vt[(bh*64+d)][s] bf16 AND xb (linear bf16) in one pass
__global__ __launch_bounds__(256) void prep_vt(const float* __restrict__ x,
                                               unsigned short* __restrict__ vt,
                                               unsigned short* __restrict__ xb) {
  int bh = blockIdx.y, b = bh >> 4, h = bh & 15;
  int s0 = blockIdx.x * 64;
  __shared__ unsigned short t[64][65];   // [d][s]
  int tid = threadIdx.x;
  int r = tid >> 2, c4 = (tid & 3) * 16;
#pragma unroll
  for (int j = 0; j < 16; j += 4) {
    float4 v = *(const float4*)(x + (size_t)(b * 2048 + s0 + r) * 1024 + h * 64 + c4 + j);
    ushort4 o;
    o.x = f2bf(v.x); o.y = f2bf(v.y); o.z = f2bf(v.z); o.w = f2bf(v.w);
    t[c4 + j + 0][r] = o.x;
    t[c4 + j + 1][r] = o.y;
    t[c4 + j + 2][r] = o.z;
    t[c4 + j + 3][r] = o.w;
    *(ushort4*)(xb + (size_t)(b * 2048 + s0 + r) * 1024 + h * 64 + c4 + j) = o;
  }
  __syncthreads();
  short8 o0, o1;
#pragma unroll
  for (int j = 0; j < 8; j++) {
    o0[j] = (short)t[r][c4 + j];
    o1[j] = (short)t[r][c4 + 8 + j];
  }
  *(short8*)(vt + (size_t)(bh * 64 + r) * 2048 + s0 + c4) = o0;
  *(short8*)(vt + (size_t)(bh * 64 + r) * 2048 + s0 + c4 + 8) = o1;
}

// ------------- fused projection GEMM: [Q|K] = xb · [Rt|Et]^T -------------
// Bw = rt base; rows 0..1023 = Rt (Q), 1024..2047 = Et (K), contiguous.
// 128x128 tile, BK=64, 4 waves 2x2, 16x16x32 MFMA, m97 structure.
__global__ __launch_bounds__(256) void gemm_qk2(const unsigned short* __restrict__ A,
                                                const unsigned short* __restrict__ Bw,
                                                unsigned short* __restrict__ qb,
                                                unsigned short* __restrict__ kb,
                                                float qs) {
  int m0 = blockIdx.x * 128, n0 = blockIdx.y * 128;
  int tid = threadIdx.x;
  int w = tid >> 6, l = tid & 63;
  int wr = w >> 1, wc = w & 1;
  int l15 = l & 15, lq = l >> 4;

  __shared__ unsigned short As[128 * 64];
  __shared__ unsigned short Bs[128 * 64];

  f32x4 acc[4][4] = {};

  for (int k0 = 0; k0 < 1024; k0 += 64) {
    __syncthreads();
#pragma unroll
    for (int i = 0; i < 4; i++) {
      int row = i * 32 + (tid >> 3), ch = tid & 7;
      gl16(A  + (size_t)(m0 + row) * 1024 + k0 + ((ch ^ (row & 7)) << 3),
           (char*)As + i * 4096 + w * 1024);
      gl16(Bw + (size_t)(n0 + row) * 1024 + k0 + ((ch ^ (row & 7)) << 3),
           (char*)Bs + i * 4096 + w * 1024);
    }
    __syncthreads();

    short8 af[4][2], bfr[4][2];
#pragma unroll
    for (int mf = 0; mf < 4; mf++)
#pragma unroll
      for (int kk = 0; kk < 2; kk++) {
        int row = wr * 64 + mf * 16 + l15;
        int kb2 = (kk * 32 + lq * 8) * 2;
        af[mf][kk] = *(const short8*)((const char*)As + row * 128 + (kb2 ^ ((row & 7) << 4)));
      }
#pragma unroll
    for (int nf = 0; nf < 4; nf++)
#pragma unroll
      for (int kk = 0; kk < 2; kk++) {
        int row = wc * 64 + nf * 16 + l15;
        int kb2 = (kk * 32 + lq * 8) * 2;
        bfr[nf][kk] = *(const short8*)((const char*)Bs + row * 128 + (kb2 ^ ((row & 7) << 4)));
      }
#pragma unroll
    for (int mf = 0; mf < 4; mf++)
#pragma unroll
      for (int nf = 0; nf < 4; nf++)
#pragma unroll
        for (int kk = 0; kk < 2; kk++)
          acc[mf][nf] = __builtin_amdgcn_mfma_f32_16x16x32_bf16(
              af[mf][kk], bfr[nf][kk], acc[mf][nf], 0, 0, 0);
  }

  unsigned short* out = (n0 < 1024) ? qb : kb;
  float scale = (n0 < 1024) ? qs : 1.0f;
  int cb = n0 & 1023;
#pragma unroll
  for (int mf = 0; mf < 4; mf++)
#pragma unroll
    for (int nf = 0; nf < 4; nf++)
#pragma unroll
      for (int r = 0; r < 4; r++) {
        int grow = m0 + wr * 64 + mf * 16 + lq * 4 + r;
        int gcol = cb + wc * 64 + nf * 16 + l15;
        out[(size_t)grow * 1024 + gcol] = f2bf(acc[mf][nf][r] * scale);
      }
}

// ---------------- flash attention ----------------
// 256 thr = 4 waves, wave owns 32 q-rows, KVBLK=64, K+V double-buffered (32KB).
// T4 counted-vmcnt pipeline: stage(next tile) -> s_waitcnt vmcnt(4) (only the
// CURRENT tile's 4 loads, issued one tile earlier) -> s_barrier -> compute ->
// s_barrier. Next tile's loads stay in flight across both barriers (no drain).
__global__ __launch_bounds__(256, 4) void attn_k(const unsigned short* __restrict__ Q,
                                                 const unsigned short* __restrict__ K,
                                                 const unsigned short* __restrict__ VT,
                                                 unsigned short* __restrict__ ctx) {
  int f = blockIdx.x;
  int bh = ((f >> 7) << 3) | (f & 7);   // cluster a head's q-tiles on one XCD
  int qt = (f >> 3) & 15;
  int b = bh >> 4, h = bh & 15;
  int q0 = qt * 128;
  int tid = threadIdx.x;
  int w = tid >> 6, l = tid & 63;
  int lh = l >> 5, l31 = l & 31;

  __shared__ unsigned short Kl[2 * 64 * 64];   // [buf][t'][d], swizzled
  __shared__ unsigned short Vl[2 * 64 * 64];   // [buf][d][t'], swizzled

  // Q fragments (B-operand): lane holds Q[q=l31][d = dk*16 + lh*8 + j]
  int qrow = q0 + w * 32 + l31;
  const unsigned short* qp = Q + (size_t)(b * 2048 + qrow) * 1024 + h * 64;
  short8 qf[4];
#pragma unroll
  for (int dk = 0; dk < 4; dk++) qf[dk] = *(const short8*)(qp + dk * 16 + lh * 8);

  // precomputed lane-invariant LDS byte offsets (swizzle key fixed per lane)
  int key = (l31 & 7) << 4;
  int koff[4], voff[4];
#pragma unroll
  for (int dk = 0; dk < 4; dk++) koff[dk] = l31 * 128 + ((dk * 32 + lh * 16) ^ key);
#pragma unroll
  for (int tf = 0; tf < 2; tf++)
#pragma unroll
    for (int kk = 0; kk < 2; kk++)
      voff[tf * 2 + kk] = l31 * 128 + ((tf * 64 + kk * 32 + lh * 16) ^ key);

  const char* KB = (const char*)Kl;
  const char* VB = (const char*)Vl;

  f32x16 cacc[2] = {};
  float mrun = -INFINITY, lsl = 0.f;

  // barrier WITHOUT waitcnt drain; fenced against compiler reordering
#define BAR()                                                                 \
  do {                                                                        \
    __builtin_amdgcn_sched_barrier(0);                                        \
    asm volatile("" ::: "memory");                                            \
    __builtin_amdgcn_s_barrier();                                             \
    asm volatile("" ::: "memory");                                            \
    __builtin_amdgcn_sched_barrier(0);                                        \
  } while (0)

#define STAGE(buf, tt)                                                        \
  {                                                                           \
    _Pragma("unroll") for (int i_ = 0; i_ < 2; i_++) {                        \
      int row_ = i_ * 32 + (tid >> 3), ch_ = tid & 7;                         \
      gl16(K + (size_t)(b * 2048 + (tt) + row_) * 1024 + h * 64 +             \
               ((ch_ ^ (row_ & 7)) << 3),                                     \
           (char*)Kl + (buf) * 8192 + i_ * 4096 + w * 1024);                  \
      gl16(VT + (size_t)(bh * 64 + row_) * 2048 + (tt) +                      \
               ((ch_ ^ (row_ & 7)) << 3),                                     \
           (char*)Vl + (buf) * 8192 + i_ * 4096 + w * 1024);                  \
    }                                                                         \
  }

#define COMPUTE(IMM)                                                          \
  do {                                                                        \
    f32x16 sacc[2] = {};                                                      \
    __builtin_amdgcn_s_setprio(1);                                            \
    _Pragma("unroll") for (int tf = 0; tf < 2; tf++)                          \
      _Pragma("unroll") for (int dk = 0; dk < 4; dk++) {                      \
        short8 kf = *(const short8*)(KB + koff[dk] + (IMM) + tf * 4096);      \
        sacc[tf] = __builtin_amdgcn_mfma_f32_32x32x16_bf16(kf, qf[dk],        \
                                                           sacc[tf], 0, 0, 0);\
      }                                                                       \
    __builtin_amdgcn_s_setprio(0);                                            \
    float t16[16];                                                            \
    _Pragma("unroll") for (int j = 0; j < 16; j++)                            \
      t16[j] = fmaxf(sacc[0][j], sacc[1][j]);                                 \
    float t8[8];                                                              \
    _Pragma("unroll") for (int j = 0; j < 8; j++)                             \
      t8[j] = fmaxf(t16[j], t16[j + 8]);                                      \
    float lmax = m3(m3(t8[0], t8[1], t8[2]), m3(t8[3], t8[4], t8[5]),         \
                    fmaxf(t8[6], t8[7]));                                     \
    if (!__all(lmax <= mrun + 8.f)) {                                         \
      unsigned lu = __builtin_bit_cast(unsigned, lmax);                       \
      auto rr = __builtin_amdgcn_permlane32_swap(lu, lu, false, false);       \
      float pm = fmaxf(__builtin_bit_cast(float, rr[0]),                      \
                       __builtin_bit_cast(float, rr[1]));                     \
      float mnew = fmaxf(mrun, pm);                                           \
      float alpha = hexp2(mrun - mnew);                                       \
      mrun = mnew; lsl *= alpha;                                              \
      _Pragma("unroll") for (int r = 0; r < 16; r++) {                        \
        int rowq = (r & 3) + ((r >> 2) << 3) + (lh << 2);                     \
        float ar = __shfl(alpha, rowq, 64);                                   \
        cacc[0][r] *= ar; cacc[1][r] *= ar;                                   \
      }                                                                       \
    }                                                                         \
    f32x2 negm2; negm2[0] = -mrun; negm2[1] = -mrun;                          \
    f32x2 r2; r2[0] = 0.f; r2[1] = 0.f;                                       \
    _Pragma("unroll") for (int tf = 0; tf < 2; tf++) {                        \
      unsigned pw[8];                                                         \
      _Pragma("unroll") for (int j = 0; j < 8; j++) {                         \
        f32x2 s2; s2[0] = sacc[tf][2 * j]; s2[1] = sacc[tf][2 * j + 1];       \
        f32x2 d = pkadd(s2, negm2);                                           \
        float e0 = hexp2(d[0]), e1 = hexp2(d[1]);                             \
        f32x2 e2; e2[0] = e0; e2[1] = e1;                                     \
        r2 = pkadd(r2, e2);                                                   \
        pw[j] = cvtpk2(e0, e1);                                               \
      }                                                                       \
      short8 pa[2];                                                           \
      _Pragma("unroll") for (int kk = 0; kk < 2; kk++) {                      \
        auto r02 = __builtin_amdgcn_permlane32_swap(pw[kk * 4 + 0],           \
                                                    pw[kk * 4 + 2], false, false); \
        auto r13 = __builtin_amdgcn_permlane32_swap(pw[kk * 4 + 1],           \
                                                    pw[kk * 4 + 3], false, false); \
        union { unsigned u[4]; short8 s8; } wv;                               \
        wv.u[0] = r02[0]; wv.u[1] = r13[0];                                   \
        wv.u[2] = r02[1]; wv.u[3] = r13[1];                                   \
        pa[kk] = wv.s8;                                                       \
      }                                                                       \
      __builtin_amdgcn_s_setprio(1);                                          \
      _Pragma("unroll") for (int kk = 0; kk < 2; kk++)                        \
        _Pragma("unroll") for (int df = 0; df < 2; df++) {                    \
          short8 vf = *(const short8*)(VB + voff[tf * 2 + kk] + (IMM) +       \
                                       df * 4096);                            \
          cacc[df] = __builtin_amdgcn_mfma_f32_32x32x16_bf16(pa[kk], vf,      \
                                                             cacc[df], 0, 0, 0); \
        }                                                                     \
      __builtin_amdgcn_s_setprio(0);                                          \
    }                                                                         \
    lsl += r2[0] + r2[1];                                                     \
  } while (0)

  STAGE(0, 0);

  for (int tc2 = 0; tc2 < 16; tc2++) {
    int t0 = tc2 * 128;
    // ---- tile 2*tc2 in buf0 ----
    STAGE(1, t0 + 64);
    asm volatile("s_waitcnt vmcnt(4)" ::: "memory");
    BAR();
    COMPUTE(0);
    BAR();
    // ---- tile 2*tc2+1 in buf1 ----
    if (tc2 < 15) {
      STAGE(0, t0 + 128);
      asm volatile("s_waitcnt vmcnt(4)" ::: "memory");
    } else {
      asm volatile("s_waitcnt vmcnt(0)" ::: "memory");
    }
    BAR();
    COMPUTE(8192);
    BAR();
  }
#undef STAGE
#undef COMPUTE
#undef BAR

  // epilogue: combine pair sums, normalize, store bf16
  {
    unsigned lu = __builtin_bit_cast(unsigned, lsl);
    auto rr = __builtin_amdgcn_permlane32_swap(lu, lu, false, false);
    lsl = __builtin_bit_cast(float, rr[0]) + __builtin_bit_cast(float, rr[1]);
  }
  float linv = 1.f / lsl;
#pragma unroll
  for (int r = 0; r < 16; r++) {
    int rowq = (r & 3) + ((r >> 2) << 3) + (lh << 2);
    float lr = __shfl(linv, rowq, 64);
    size_t base = (size_t)(b * 2048 + q0 + w * 32 + rowq) * 1024 + h * 64 + l31;
    ctx[base]      = f2bf(cacc[0][r] * lr);
    ctx[base + 32] = f2bf(cacc[1][r] * lr);
  }
}

// ---------------- residual + LayerNorm (bf16 ctx input) ----------------
__global__ __launch_bounds__(256) void ln_k(const unsigned short* __restrict__ ctx,
                                            const float* __restrict__ x,
                                            const float* __restrict__ wgt,
                                            const float* __restrict__ bgam,
                                            float* __restrict__ out) {
  int row = blockIdx.x;
  int tid = threadIdx.x;
  size_t base = (size_t)row * 1024 + tid * 4;
  ushort4 cu = *(const ushort4*)(ctx + base);
  float4 xv = *(const float4*)(x + base);
  float4 y;
  y.x = bf2f(cu.x) + xv.x; y.y = bf2f(cu.y) + xv.y;
  y.z = bf2f(cu.z) + xv.z; y.w = bf2f(cu.w) + xv.w;
  float s  = y.x + y.y + y.z + y.w;
  float ss = y.x * y.x + y.y * y.y + y.z * y.z + y.w * y.w;
#pragma unroll
  for (int o = 32; o >= 1; o >>= 1) {
    s  += __shfl_xor(s, o, 64);
    ss += __shfl_xor(ss, o, 64);
  }
  __shared__ float sm[8];
  if ((tid & 63) == 0) { sm[(tid >> 6) * 2] = s; sm[(tid >> 6) * 2 + 1] = ss; }
  __syncthreads();
  s  = sm[0] + sm[2] + sm[4] + sm[6];
  ss = sm[1] + sm[3] + sm[5] + sm[7];
  float mu = s * (1.f / 1024.f);
  float var = ss * (1.f / 1024.f) - mu * mu;
  float rstd = rsqrtf(var + 1e-5f);
  float4 wv = *(const float4*)(wgt + tid * 4);
  float4 bv = *(const float4*)(bgam + tid * 4);
  float4 o4;
  o4.x = (y.x - mu) * rstd * wv.x + bv.x;
  o4.y = (y.y - mu) * rstd * wv.y + bv.y;
  o4.z = (y.z - mu) * rstd * wv.z + bv.z;
  o4.w = (y.w - mu) * rstd * wv.w + bv.w;
  *(float4*)(out + base) = o4;
}

// ---------------- launch ----------------
extern "C" void kernel_launch(void* const* d_in, const int* in_sizes, int n_in,
                              void* d_out, int out_size, void* d_ws, size_t ws_size,
                              hipStream_t stream) {
  (void)in_sizes; (void)n_in; (void)out_size; (void)ws_size;
  const float* R  = (const float*)d_in[0];
  const float* En = (const float*)d_in[1];
  const float* x  = (const float*)d_in[2];
  const float* lw = (const float*)d_in[3];
  const float* lb = (const float*)d_in[4];
  float* out = (float*)d_out;

  char* ws = (char*)d_ws;
  unsigned short* xb  = (unsigned short*)(ws);                       // 16 MB bf16 x
  unsigned short* qb  = (unsigned short*)(ws + (size_t)(16u << 20)); // 16 MB Q
  unsigned short* kb  = (unsigned short*)(ws + (size_t)(32u << 20)); // 16 MB K
  unsigned short* vt  = (unsigned short*)(ws + (size_t)(48u << 20)); // 16 MB V^T
  unsigned short* ctx = (unsigned short*)(ws + (size_t)(64u << 20)); // 16 MB context bf16
  unsigned short* rt  = (unsigned short*)(ws + (size_t)(96u << 20)); // 2 MB R^T
  unsigned short* et  = (unsigned short*)(ws + (size_t)(98u << 20)); // 2 MB E^T (contiguous after rt)

  prep_wt<<<dim3(16, 16, 2), 256, 0, stream>>>(R, En, rt, et);
  prep_vt<<<dim3(32, 64), 256, 0, stream>>>(x, vt, xb);
  gemm_qk2<<<dim3(64, 16), 256, 0, stream>>>(xb, rt, qb, kb, 0.125f * LOG2E);
  attn_k<<<1024, 256, 0, stream>>>(qb, kb, vt, ctx);
  ln_k<<<8192, 256, 0, stream>>>(ctx, x, lw, lb, out);
}

// Round 7
// 243.902 us; speedup vs baseline: 1.3656x; 1.0185x over previous
//
#include <hip/hip_runtime.h>
#include <hip/hip_bf16.h>

// ---- constants ----
// B=4, S=2048, E=1024, H=16, D=64, scale = 0.125, LN eps 1e-5
#define LOG2E 1.44269504088896340736f

typedef __attribute__((ext_vector_type(8)))  short  short8;
typedef __attribute__((ext_vector_type(2)))  float  f32x2;
typedef __attribute__((ext_vector_type(4)))  float  f32x4;
typedef __attribute__((ext_vector_type(16))) float  f32x16;

__device__ __forceinline__ unsigned short f2bf(float f) {
  unsigned u = __builtin_bit_cast(unsigned, f);
  return (unsigned short)((u + 0x8000u) >> 16);
}
__device__ __forceinline__ float bf2f(unsigned short u) {
  return __builtin_bit_cast(float, (unsigned)u << 16);
}
__device__ __forceinline__ f32x2 pkadd(f32x2 a, f32x2 b) {
  f32x2 r; asm("v_pk_add_f32 %0, %1, %2" : "=v"(r) : "v"(a), "v"(b)); return r;
}
__device__ __forceinline__ unsigned cvtpk2(float a, float b) {
  unsigned r; asm("v_cvt_pk_bf16_f32 %0, %1, %2" : "=v"(r) : "v"(a), "v"(b)); return r;
}
__device__ __forceinline__ float hexp2(float x) {
  float r; asm("v_exp_f32 %0, %1" : "=v"(r) : "v"(x)); return r;
}
__device__ __forceinline__ float m3(float a, float b, float c) {
  return fmaxf(fmaxf(a, b), c);
}
__device__ __forceinline__ void gl16(const void* g, void* l) {
  __builtin_amdgcn_global_load_lds(
      (const __attribute__((address_space(1))) void*)g,
      (__attribute__((address_space(3))) void*)l, 16, 0, 0);
}

// ---------------- prep kernels ----------------

__global__ __launch_bounds__(256) void prep_wt(const float* __restrict__ R,
                                               const float* __restrict__ En,
                                               unsigned short* __restrict__ Rt,
                                               unsigned short* __restrict__ Et) {
  const float* src = blockIdx.z ? En : R;
  unsigned short* dst = blockIdx.z ? Et : Rt;
  __shared__ unsigned short t[64][65];
  int e0 = blockIdx.y * 64, f0 = blockIdx.x * 64;
  int tid = threadIdx.x;
  int r = tid >> 2, c4 = (tid & 3) * 16;
#pragma unroll
  for (int j = 0; j < 16; j += 4) {
    float4 v = *(const float4*)(src + (size_t)(e0 + r) * 1024 + f0 + c4 + j);
    t[c4 + j + 0][r] = f2bf(v.x);
    t[c4 + j + 1][r] = f2bf(v.y);
    t[c4 + j + 2][r] = f2bf(v.z);
    t[c4 + j + 3][r] = f2bf(v.w);
  }
  __syncthreads();
  short8 o0, o1;
#pragma unroll
  for (int j = 0; j < 8; j++) {
    o0[j] = (short)t[r][c4 + j];
    o1[j] = (short)t[r][c4 + 8 + j];
  }
  *(short8*)(dst + (size_t)(f0 + r) * 1024 + e0 + c4) = o0;
  *(short8*)(dst + (size_t)(f0 + r) * 1024 + e0 + c4 + 8) = o1;
}

__global__ __launch_bounds__(256) void prep_vt(const float* __restrict__ x,
                                               unsigned short* __restrict__ vt,
                                               unsigned short* __restrict__ xb) {
  int bh = blockIdx.y, b = bh >> 4, h = bh & 15;
  int s0 = blockIdx.x * 64;
  __shared__ unsigned short t[64][65];   // [d][s]
  int tid = threadIdx.x;
  int r = tid >> 2, c4 = (tid & 3) * 16;
#pragma unroll
  for (int j = 0; j < 16; j += 4) {
    float4 v = *(const float4*)(x + (size_t)(b * 2048 + s0 + r) * 1024 + h * 64 + c4 + j);
    ushort4 o;
    o.x = f2bf(v.x); o.y = f2bf(v.y); o.z = f2bf(v.z); o.w = f2bf(v.w);
    t[c4 + j + 0][r] = o.x;
    t[c4 + j + 1][r] = o.y;
    t[c4 + j + 2][r] = o.z;
    t[c4 + j + 3][r] = o.w;
    *(ushort4*)(xb + (size_t)(b * 2048 + s0 + r) * 1024 + h * 64 + c4 + j) = o;
  }
  __syncthreads();
  short8 o0, o1;
#pragma unroll
  for (int j = 0; j < 8; j++) {
    o0[j] = (short)t[r][c4 + j];
    o1[j] = (short)t[r][c4 + 8 + j];
  }
  *(short8*)(vt + (size_t)(bh * 64 + r) * 2048 + s0 + c4) = o0;
  *(short8*)(vt + (size_t)(bh * 64 + r) * 2048 + s0 + c4 + 8) = o1;
}

// ------------- 8-phase 256x256 projection GEMM: [Q|K] = xb · [Rt|Et]^T ------
// BM=BN=256, BK=64, 512 thr = 8 waves (2M x 4N), wave output 128x64.
// 4 phases per K-tile, each = one 64x32 C-quadrant (16 MFMA) + 12 ds_read_b128
// + staging 2 half-tiles of tile kt+1 (phases 0,1) + raw s_barrier.
// Single vmcnt(0) per tile; its loads are >=2 phases old (latency covered).
// LDS 128KB: As[2buf][2half][128][64] + Bs same, (row&7)<<4 XOR swizzle.
__global__ __launch_bounds__(512, 2) void gemm8(const unsigned short* __restrict__ A,
                                                const unsigned short* __restrict__ Bw,
                                                unsigned short* __restrict__ qb,
                                                unsigned short* __restrict__ kb,
                                                float qs) {
  int m0 = blockIdx.x * 256;
  int by = blockIdx.y;               // 0..7; <4 -> Q, >=4 -> K
  int n0 = by * 256;
  int tid = threadIdx.x;
  int w = tid >> 6, l = tid & 63;
  int wr = w >> 2, wc = w & 3;
  int l15 = l & 15, lq = l >> 4;

  __shared__ unsigned short As[2][2][128 * 64];   // 64KB
  __shared__ unsigned short Bs[2][2][128 * 64];   // 64KB

  f32x4 acc[8][4] = {};

  int key = (l15 & 7) << 4;
  const char* pA[2];
  const char* pB[2];
#pragma unroll
  for (int kk = 0; kk < 2; kk++) {
    pA[kk] = (const char*)As + wr * 16384 + l15 * 128 + ((kk * 64 + lq * 16) ^ key);
    pB[kk] = (const char*)Bs + (wc >> 1) * 16384 + ((wc & 1) * 64 + l15) * 128 +
             ((kk * 64 + lq * 16) ^ key);
  }

  // stage half `which` (0=A0,1=A1,2=B0,3=B1) of K-tile kt into buffer buf
#define SHALF(buf, kt, which)                                                 \
  do {                                                                        \
    const unsigned short* src_ = ((which) < 2)                                \
        ? (A  + (size_t)(m0 + ((which) & 1) * 128) * 1024)                    \
        : (Bw + (size_t)(n0 + ((which) & 1) * 128) * 1024);                   \
    char* dst_ = (char*)(((which) < 2) ? &As[buf][(which) & 1][0]             \
                                       : &Bs[buf][(which) & 1][0]);           \
    int k0_ = (kt) * 64;                                                      \
    _Pragma("unroll") for (int i_ = 0; i_ < 2; i_++) {                        \
      int flat_ = i_ * 512 + tid;                                             \
      int row_ = flat_ >> 3, ch_ = flat_ & 7;                                 \
      gl16(src_ + (size_t)row_ * 1024 + k0_ + ((ch_ ^ (row_ & 7)) << 3),      \
           dst_ + i_ * 8192 + w * 1024);                                      \
    }                                                                         \
  } while (0)

#define BARX()                                                                \
  do {                                                                        \
    __builtin_amdgcn_sched_barrier(0);                                        \
    asm volatile("" ::: "memory");                                            \
    __builtin_amdgcn_s_barrier();                                             \
    asm volatile("" ::: "memory");                                            \
    __builtin_amdgcn_sched_barrier(0);                                        \
  } while (0)

#define DSRD(buf, mq, nq)                                                     \
  short8 af[4][2]; short8 bfv[2][2];                                          \
  _Pragma("unroll") for (int mfq = 0; mfq < 4; mfq++)                         \
    _Pragma("unroll") for (int kk = 0; kk < 2; kk++)                          \
      af[mfq][kk] = *(const short8*)(pA[kk] + (buf) * 32768 + (mq) * 8192 +   \
                                     mfq * 2048);                             \
  _Pragma("unroll") for (int nfq = 0; nfq < 2; nfq++)                         \
    _Pragma("unroll") for (int kk = 0; kk < 2; kk++)                          \
      bfv[nfq][kk] = *(const short8*)(pB[kk] + (buf) * 32768 + (nq) * 4096 +  \
                                      nfq * 2048);

#define MM(mq, nq)                                                            \
  asm volatile("s_waitcnt lgkmcnt(0)" ::: "memory");                          \
  __builtin_amdgcn_sched_barrier(0);                                          \
  __builtin_amdgcn_s_setprio(1);                                              \
  _Pragma("unroll") for (int mfq = 0; mfq < 4; mfq++)                         \
    _Pragma("unroll") for (int nfq = 0; nfq < 2; nfq++)                       \
      _Pragma("unroll") for (int kk = 0; kk < 2; kk++)                        \
        acc[(mq) * 4 + mfq][(nq) * 2 + nfq] =                                 \
            __builtin_amdgcn_mfma_f32_16x16x32_bf16(                          \
                af[mfq][kk], bfv[nfq][kk],                                    \
                acc[(mq) * 4 + mfq][(nq) * 2 + nfq], 0, 0, 0);                \
  __builtin_amdgcn_s_setprio(0);

  // prologue: stage tile 0 into buf 0
  SHALF(0, 0, 0); SHALF(0, 0, 1); SHALF(0, 0, 2); SHALF(0, 0, 3);
  asm volatile("s_waitcnt vmcnt(0)" ::: "memory");
  BARX();

  for (int kt = 0; kt < 16; kt++) {
    int buf = kt & 1, nb = buf ^ 1;
    {  // phase 0: quadrant (0,0); stage A halves of next tile
      DSRD(buf, 0, 0);
      if (kt < 15) { SHALF(nb, kt + 1, 0); SHALF(nb, kt + 1, 1); }
      MM(0, 0);
      BARX();
    }
    {  // phase 1: quadrant (0,1); stage B halves of next tile
      DSRD(buf, 0, 1);
      if (kt < 15) { SHALF(nb, kt + 1, 2); SHALF(nb, kt + 1, 3); }
      MM(0, 1);
      BARX();
    }
    {  // phase 2: quadrant (1,0)
      DSRD(buf, 1, 0);
      MM(1, 0);
      BARX();
    }
    {  // phase 3: quadrant (1,1); tile-end: wait next tile's loads (aged >=2 phases)
      DSRD(buf, 1, 1);
      MM(1, 1);
      asm volatile("s_waitcnt vmcnt(0)" ::: "memory");
      BARX();
    }
  }
#undef SHALF
#undef DSRD
#undef MM
#undef BARX

  unsigned short* out = (by < 4) ? qb : kb;
  float scale = (by < 4) ? qs : 1.0f;
  int cb = (by & 3) * 256;
#pragma unroll
  for (int mf = 0; mf < 8; mf++)
#pragma unroll
    for (int nf = 0; nf < 4; nf++)
#pragma unroll
      for (int r = 0; r < 4; r++) {
        int grow = m0 + wr * 128 + mf * 16 + lq * 4 + r;
        int gcol = cb + wc * 64 + nf * 16 + l15;
        out[(size_t)grow * 1024 + gcol] = f2bf(acc[mf][nf][r] * scale);
      }
}

// ---------------- flash attention (round-5 form: best measured) ----------------
__global__ __launch_bounds__(256, 4) void attn_k(const unsigned short* __restrict__ Q,
                                                 const unsigned short* __restrict__ K,
                                                 const unsigned short* __restrict__ VT,
                                                 unsigned short* __restrict__ ctx) {
  int f = blockIdx.x;
  int bh = ((f >> 7) << 3) | (f & 7);   // cluster a head's q-tiles on one XCD
  int qt = (f >> 3) & 15;
  int b = bh >> 4, h = bh & 15;
  int q0 = qt * 128;
  int tid = threadIdx.x;
  int w = tid >> 6, l = tid & 63;
  int lh = l >> 5, l31 = l & 31;

  __shared__ unsigned short Kl[2 * 64 * 64];   // [buf][t'][d], swizzled
  __shared__ unsigned short Vl[2 * 64 * 64];   // [buf][d][t'], swizzled

  int qrow = q0 + w * 32 + l31;
  const unsigned short* qp = Q + (size_t)(b * 2048 + qrow) * 1024 + h * 64;
  short8 qf[4];
#pragma unroll
  for (int dk = 0; dk < 4; dk++) qf[dk] = *(const short8*)(qp + dk * 16 + lh * 8);

  int key = (l31 & 7) << 4;
  int koff[4], voff[4];
#pragma unroll
  for (int dk = 0; dk < 4; dk++) koff[dk] = l31 * 128 + ((dk * 32 + lh * 16) ^ key);
#pragma unroll
  for (int tf = 0; tf < 2; tf++)
#pragma unroll
    for (int kk = 0; kk < 2; kk++)
      voff[tf * 2 + kk] = l31 * 128 + ((tf * 64 + kk * 32 + lh * 16) ^ key);

  const char* KB = (const char*)Kl;
  const char* VB = (const char*)Vl;

  f32x16 cacc[2] = {};
  float mrun = -INFINITY, lsl = 0.f;

#define STAGE(buf, tt)                                                        \
  {                                                                           \
    _Pragma("unroll") for (int i_ = 0; i_ < 2; i_++) {                        \
      int row_ = i_ * 32 + (tid >> 3), ch_ = tid & 7;                         \
      gl16(K + (size_t)(b * 2048 + (tt) + row_) * 1024 + h * 64 +             \
               ((ch_ ^ (row_ & 7)) << 3),                                     \
           (char*)Kl + (buf) * 8192 + i_ * 4096 + w * 1024);                  \
      gl16(VT + (size_t)(bh * 64 + row_) * 2048 + (tt) +                      \
               ((ch_ ^ (row_ & 7)) << 3),                                     \
           (char*)Vl + (buf) * 8192 + i_ * 4096 + w * 1024);                  \
    }                                                                         \
  }

#define COMPUTE(IMM)                                                          \
  do {                                                                        \
    f32x16 sacc[2] = {};                                                      \
    __builtin_amdgcn_s_setprio(1);                                            \
    _Pragma("unroll") for (int tf = 0; tf < 2; tf++)                          \
      _Pragma("unroll") for (int dk = 0; dk < 4; dk++) {                      \
        short8 kf = *(const short8*)(KB + koff[dk] + (IMM) + tf * 4096);      \
        sacc[tf] = __builtin_amdgcn_mfma_f32_32x32x16_bf16(kf, qf[dk],        \
                                                           sacc[tf], 0, 0, 0);\
      }                                                                       \
    __builtin_amdgcn_s_setprio(0);                                            \
    float t16[16];                                                            \
    _Pragma("unroll") for (int j = 0; j < 16; j++)                            \
      t16[j] = fmaxf(sacc[0][j], sacc[1][j]);                                 \
    float t8[8];                                                              \
    _Pragma("unroll") for (int j = 0; j < 8; j++)                             \
      t8[j] = fmaxf(t16[j], t16[j + 8]);                                      \
    float lmax = m3(m3(t8[0], t8[1], t8[2]), m3(t8[3], t8[4], t8[5]),         \
                    fmaxf(t8[6], t8[7]));                                     \
    if (!__all(lmax <= mrun + 8.f)) {                                         \
      unsigned lu = __builtin_bit_cast(unsigned, lmax);                       \
      auto rr = __builtin_amdgcn_permlane32_swap(lu, lu, false, false);       \
      float pm = fmaxf(__builtin_bit_cast(float, rr[0]),                      \
                       __builtin_bit_cast(float, rr[1]));                     \
      float mnew = fmaxf(mrun, pm);                                           \
      float alpha = hexp2(mrun - mnew);                                       \
      mrun = mnew; lsl *= alpha;                                              \
      _Pragma("unroll") for (int r = 0; r < 16; r++) {                        \
        int rowq = (r & 3) + ((r >> 2) << 3) + (lh << 2);                     \
        float ar = __shfl(alpha, rowq, 64);                                   \
        cacc[0][r] *= ar; cacc[1][r] *= ar;                                   \
      }                                                                       \
    }                                                                         \
    f32x2 negm2; negm2[0] = -mrun; negm2[1] = -mrun;                          \
    f32x2 r2; r2[0] = 0.f; r2[1] = 0.f;                                       \
    _Pragma("unroll") for (int tf = 0; tf < 2; tf++) {                        \
      unsigned pw[8];                                                         \
      _Pragma("unroll") for (int j = 0; j < 8; j++) {                         \
        f32x2 s2; s2[0] = sacc[tf][2 * j]; s2[1] = sacc[tf][2 * j + 1];       \
        f32x2 d = pkadd(s2, negm2);                                           \
        float e0 = hexp2(d[0]), e1 = hexp2(d[1]);                             \
        f32x2 e2; e2[0] = e0; e2[1] = e1;                                     \
        r2 = pkadd(r2, e2);                                                   \
        pw[j] = cvtpk2(e0, e1);                                               \
      }                                                                       \
      short8 pa[2];                                                           \
      _Pragma("unroll") for (int kk = 0; kk < 2; kk++) {                      \
        auto r02 = __builtin_amdgcn_permlane32_swap(pw[kk * 4 + 0],           \
                                                    pw[kk * 4 + 2], false, false); \
        auto r13 = __builtin_amdgcn_permlane32_swap(pw[kk * 4 + 1],           \
                                                    pw[kk * 4 + 3], false, false); \
        union { unsigned u[4]; short8 s8; } wv;                               \
        wv.u[0] = r02[0]; wv.u[1] = r13[0];                                   \
        wv.u[2] = r02[1]; wv.u[3] = r13[1];                                   \
        pa[kk] = wv.s8;                                                       \
      }                                                                       \
      __builtin_amdgcn_s_setprio(1);                                          \
      _Pragma("unroll") for (int kk = 0; kk < 2; kk++)                        \
        _Pragma("unroll") for (int df = 0; df < 2; df++) {                    \
          short8 vf = *(const short8*)(VB + voff[tf * 2 + kk] + (IMM) +       \
                                       df * 4096);                            \
          cacc[df] = __builtin_amdgcn_mfma_f32_32x32x16_bf16(pa[kk], vf,      \
                                                             cacc[df], 0, 0, 0); \
        }                                                                     \
      __builtin_amdgcn_s_setprio(0);                                          \
    }                                                                         \
    lsl += r2[0] + r2[1];                                                     \
  } while (0)

  STAGE(0, 0);
  __syncthreads();

  for (int tc2 = 0; tc2 < 16; tc2++) {
    int t0 = tc2 * 128;
    STAGE(1, t0 + 64);
    COMPUTE(0);
    __syncthreads();
    if (tc2 < 15) STAGE(0, t0 + 128);
    COMPUTE(8192);
    __syncthreads();
  }
#undef STAGE
#undef COMPUTE

  {
    unsigned lu = __builtin_bit_cast(unsigned, lsl);
    auto rr = __builtin_amdgcn_permlane32_swap(lu, lu, false, false);
    lsl = __builtin_bit_cast(float, rr[0]) + __builtin_bit_cast(float, rr[1]);
  }
  float linv = 1.f / lsl;
#pragma unroll
  for (int r = 0; r < 16; r++) {
    int rowq = (r & 3) + ((r >> 2) << 3) + (lh << 2);
    float lr = __shfl(linv, rowq, 64);
    size_t base = (size_t)(b * 2048 + q0 + w * 32 + rowq) * 1024 + h * 64 + l31;
    ctx[base]      = f2bf(cacc[0][r] * lr);
    ctx[base + 32] = f2bf(cacc[1][r] * lr);
  }
}

// ---------------- residual + LayerNorm (bf16 ctx input) ----------------
__global__ __launch_bounds__(256) void ln_k(const unsigned short* __restrict__ ctx,
                                            const float* __restrict__ x,
                                            const float* __restrict__ wgt,
                                            const float* __restrict__ bgam,
                                            float* __restrict__ out) {
  int row = blockIdx.x;
  int tid = threadIdx.x;
  size_t base = (size_t)row * 1024 + tid * 4;
  ushort4 cu = *(const ushort4*)(ctx + base);
  float4 xv = *(const float4*)(x + base);
  float4 y;
  y.x = bf2f(cu.x) + xv.x; y.y = bf2f(cu.y) + xv.y;
  y.z = bf2f(cu.z) + xv.z; y.w = bf2f(cu.w) + xv.w;
  float s  = y.x + y.y + y.z + y.w;
  float ss = y.x * y.x + y.y * y.y + y.z * y.z + y.w * y.w;
#pragma unroll
  for (int o = 32; o >= 1; o >>= 1) {
    s  += __shfl_xor(s, o, 64);
    ss += __shfl_xor(ss, o, 64);
  }
  __shared__ float sm[8];
  if ((tid & 63) == 0) { sm[(tid >> 6) * 2] = s; sm[(tid >> 6) * 2 + 1] = ss; }
  __syncthreads();
  s  = sm[0] + sm[2] + sm[4] + sm[6];
  ss = sm[1] + sm[3] + sm[5] + sm[7];
  float mu = s * (1.f / 1024.f);
  float var = ss * (1.f / 1024.f) - mu * mu;
  float rstd = rsqrtf(var + 1e-5f);
  float4 wv = *(const float4*)(wgt + tid * 4);
  float4 bv = *(const float4*)(bgam + tid * 4);
  float4 o4;
  o4.x = (y.x - mu) * rstd * wv.x + bv.x;
  o4.y = (y.y - mu) * rstd * wv.y + bv.y;
  o4.z = (y.z - mu) * rstd * wv.z + bv.z;
  o4.w = (y.w - mu) * rstd * wv.w + bv.w;
  *(float4*)(out + base) = o4;
}

// ---------------- launch ----------------
extern "C" void kernel_launch(void* const* d_in, const int* in_sizes, int n_in,
                              void* d_out, int out_size, void* d_ws, size_t ws_size,
                              hipStream_t stream) {
  (void)in_sizes; (void)n_in; (void)out_size; (void)ws_size;
  const float* R  = (const float*)d_in[0];
  const float* En = (const float*)d_in[1];
  const float* x  = (const float*)d_in[2];
  const float* lw = (const float*)d_in[3];
  const float* lb = (const float*)d_in[4];
  float* out = (float*)d_out;

  char* ws = (char*)d_ws;
  unsigned short* xb  = (unsigned short*)(ws);                       // 16 MB bf16 x
  unsigned short* qb  = (unsigned short*)(ws + (size_t)(16u << 20)); // 16 MB Q
  unsigned short* kb  = (unsigned short*)(ws + (size_t)(32u << 20)); // 16 MB K
  unsigned short* vt  = (unsigned short*)(ws + (size_t)(48u << 20)); // 16 MB V^T
  unsigned short* ctx = (unsigned short*)(ws + (size_t)(64u << 20)); // 16 MB context bf16
  unsigned short* rt  = (unsigned short*)(ws + (size_t)(96u << 20)); // 2 MB R^T
  unsigned short* et  = (unsigned short*)(ws + (size_t)(98u << 20)); // 2 MB E^T (contiguous)

  prep_wt<<<dim3(16, 16, 2), 256, 0, stream>>>(R, En, rt, et);
  prep_vt<<<dim3(32, 64), 256, 0, stream>>>(x, vt, xb);
  gemm8<<<dim3(32, 8), 512, 0, stream>>>(xb, rt, qb, kb, 0.125f * LOG2E);
  attn_k<<<1024, 256, 0, stream>>>(qb, kb, vt, ctx);
  ln_k<<<8192, 256, 0, stream>>>(ctx, x, lw, lb, out);
}

// Round 8
// 243.456 us; speedup vs baseline: 1.3681x; 1.0018x over previous
//
#include <hip/hip_runtime.h>
#include <hip/hip_bf16.h>

// ---- constants ----
// B=4, S=2048, E=1024, H=16, D=64, scale = 0.125, LN eps 1e-5
#define LOG2E 1.44269504088896340736f

typedef __attribute__((ext_vector_type(8)))  short  short8;
typedef __attribute__((ext_vector_type(2)))  float  f32x2;
typedef __attribute__((ext_vector_type(4)))  float  f32x4;
typedef __attribute__((ext_vector_type(16))) float  f32x16;

__device__ __forceinline__ unsigned short f2bf(float f) {
  unsigned u = __builtin_bit_cast(unsigned, f);
  return (unsigned short)((u + 0x8000u) >> 16);
}
__device__ __forceinline__ float bf2f(unsigned short u) {
  return __builtin_bit_cast(float, (unsigned)u << 16);
}
__device__ __forceinline__ f32x2 pkadd(f32x2 a, f32x2 b) {
  f32x2 r; asm("v_pk_add_f32 %0, %1, %2" : "=v"(r) : "v"(a), "v"(b)); return r;
}
__device__ __forceinline__ unsigned cvtpk2(float a, float b) {
  unsigned r; asm("v_cvt_pk_bf16_f32 %0, %1, %2" : "=v"(r) : "v"(a), "v"(b)); return r;
}
__device__ __forceinline__ float hexp2(float x) {
  float r; asm("v_exp_f32 %0, %1" : "=v"(r) : "v"(x)); return r;
}
__device__ __forceinline__ float m3(float a, float b, float c) {
  return fmaxf(fmaxf(a, b), c);
}
__device__ __forceinline__ void gl16(const void* g, void* l) {
  __builtin_amdgcn_global_load_lds(
      (const __attribute__((address_space(1))) void*)g,
      (__attribute__((address_space(3))) void*)l, 16, 0, 0);
}

// ---------------- fused prep: x->vt/xb (blocks<2048) + W->Wt (blocks>=2048) --
__global__ __launch_bounds__(256) void prep_all(const float* __restrict__ R,
                                                const float* __restrict__ En,
                                                const float* __restrict__ x,
                                                unsigned short* __restrict__ Rt,
                                                unsigned short* __restrict__ Et,
                                                unsigned short* __restrict__ vt,
                                                unsigned short* __restrict__ xb) {
  int id = blockIdx.x;
  int tid = threadIdx.x;
  __shared__ unsigned short t[64][65];
  if (id < 2048) {
    // x[b][s][h*64+d] -> vt[(bh*64+d)][s] bf16 + xb linear bf16
    int bh = id >> 5, st = id & 31;
    int b = bh >> 4, h = bh & 15;
    int s0 = st * 64;
#pragma unroll
    for (int i = 0; i < 4; i++) {
      int it = i * 256 + tid;
      int row = it >> 4, c4 = (it & 15) * 4;    // 16 lanes cover 256B contiguous
      size_t goff = (size_t)(b * 2048 + s0 + row) * 1024 + h * 64 + c4;
      float4 v = *(const float4*)(x + goff);
      ushort4 o;
      o.x = f2bf(v.x); o.y = f2bf(v.y); o.z = f2bf(v.z); o.w = f2bf(v.w);
      *(ushort4*)(xb + goff) = o;
      t[c4 + 0][row] = o.x; t[c4 + 1][row] = o.y;
      t[c4 + 2][row] = o.z; t[c4 + 3][row] = o.w;
    }
    __syncthreads();
    int r = tid >> 2, c4 = (tid & 3) * 16;
    short8 o0, o1;
#pragma unroll
    for (int j = 0; j < 8; j++) {
      o0[j] = (short)t[r][c4 + j];
      o1[j] = (short)t[r][c4 + 8 + j];
    }
    *(short8*)(vt + (size_t)(bh * 64 + r) * 2048 + s0 + c4) = o0;
    *(short8*)(vt + (size_t)(bh * 64 + r) * 2048 + s0 + c4 + 8) = o1;
  } else {
    // W[e][f] fp32 -> Wt[f][e] bf16
    int z = id - 2048;                 // 0..511
    const float* src = (z >= 256) ? En : R;
    unsigned short* dst = (z >= 256) ? Et : Rt;
    int rem = z & 255;
    int e0 = (rem >> 4) * 64, f0 = (rem & 15) * 64;
    int r = tid >> 2, c4 = (tid & 3) * 16;
#pragma unroll
    for (int j = 0; j < 16; j += 4) {
      float4 v = *(const float4*)(src + (size_t)(e0 + r) * 1024 + f0 + c4 + j);
      t[c4 + j + 0][r] = f2bf(v.x);
      t[c4 + j + 1][r] = f2bf(v.y);
      t[c4 + j + 2][r] = f2bf(v.z);
      t[c4 + j + 3][r] = f2bf(v.w);
    }
    __syncthreads();
    short8 o0, o1;
#pragma unroll
    for (int j = 0; j < 8; j++) {
      o0[j] = (short)t[r][c4 + j];
      o1[j] = (short)t[r][c4 + 8 + j];
    }
    *(short8*)(dst + (size_t)(f0 + r) * 1024 + e0 + c4) = o0;
    *(short8*)(dst + (size_t)(f0 + r) * 1024 + e0 + c4 + 8) = o1;
  }
}

// ------------- 8-phase 256x256 projection GEMM: [Q|K] = xb · [Rt|Et]^T ------
// (unchanged from round 7 — verified)
__global__ __launch_bounds__(512, 2) void gemm8(const unsigned short* __restrict__ A,
                                                const unsigned short* __restrict__ Bw,
                                                unsigned short* __restrict__ qb,
                                                unsigned short* __restrict__ kb,
                                                float qs) {
  int m0 = blockIdx.x * 256;
  int by = blockIdx.y;               // 0..7; <4 -> Q, >=4 -> K
  int n0 = by * 256;
  int tid = threadIdx.x;
  int w = tid >> 6, l = tid & 63;
  int wr = w >> 2, wc = w & 3;
  int l15 = l & 15, lq = l >> 4;

  __shared__ unsigned short As[2][2][128 * 64];   // 64KB
  __shared__ unsigned short Bs[2][2][128 * 64];   // 64KB

  f32x4 acc[8][4] = {};

  int key = (l15 & 7) << 4;
  const char* pA[2];
  const char* pB[2];
#pragma unroll
  for (int kk = 0; kk < 2; kk++) {
    pA[kk] = (const char*)As + wr * 16384 + l15 * 128 + ((kk * 64 + lq * 16) ^ key);
    pB[kk] = (const char*)Bs + (wc >> 1) * 16384 + ((wc & 1) * 64 + l15) * 128 +
             ((kk * 64 + lq * 16) ^ key);
  }

#define SHALF(buf, kt, which)                                                 \
  do {                                                                        \
    const unsigned short* src_ = ((which) < 2)                                \
        ? (A  + (size_t)(m0 + ((which) & 1) * 128) * 1024)                    \
        : (Bw + (size_t)(n0 + ((which) & 1) * 128) * 1024);                   \
    char* dst_ = (char*)(((which) < 2) ? &As[buf][(which) & 1][0]             \
                                       : &Bs[buf][(which) & 1][0]);           \
    int k0_ = (kt) * 64;                                                      \
    _Pragma("unroll") for (int i_ = 0; i_ < 2; i_++) {                        \
      int flat_ = i_ * 512 + tid;                                             \
      int row_ = flat_ >> 3, ch_ = flat_ & 7;                                 \
      gl16(src_ + (size_t)row_ * 1024 + k0_ + ((ch_ ^ (row_ & 7)) << 3),      \
           dst_ + i_ * 8192 + w * 1024);                                      \
    }                                                                         \
  } while (0)

#define BARX()                                                                \
  do {                                                                        \
    __builtin_amdgcn_sched_barrier(0);                                        \
    asm volatile("" ::: "memory");                                            \
    __builtin_amdgcn_s_barrier();                                             \
    asm volatile("" ::: "memory");                                            \
    __builtin_amdgcn_sched_barrier(0);                                        \
  } while (0)

#define DSRD(buf, mq, nq)                                                     \
  short8 af[4][2]; short8 bfv[2][2];                                          \
  _Pragma("unroll") for (int mfq = 0; mfq < 4; mfq++)                         \
    _Pragma("unroll") for (int kk = 0; kk < 2; kk++)                          \
      af[mfq][kk] = *(const short8*)(pA[kk] + (buf) * 32768 + (mq) * 8192 +   \
                                     mfq * 2048);                             \
  _Pragma("unroll") for (int nfq = 0; nfq < 2; nfq++)                         \
    _Pragma("unroll") for (int kk = 0; kk < 2; kk++)                          \
      bfv[nfq][kk] = *(const short8*)(pB[kk] + (buf) * 32768 + (nq) * 4096 +  \
                                      nfq * 2048);

#define MM(mq, nq)                                                            \
  asm volatile("s_waitcnt lgkmcnt(0)" ::: "memory");                          \
  __builtin_amdgcn_sched_barrier(0);                                          \
  __builtin_amdgcn_s_setprio(1);                                              \
  _Pragma("unroll") for (int mfq = 0; mfq < 4; mfq++)                         \
    _Pragma("unroll") for (int nfq = 0; nfq < 2; nfq++)                       \
      _Pragma("unroll") for (int kk = 0; kk < 2; kk++)                        \
        acc[(mq) * 4 + mfq][(nq) * 2 + nfq] =                                 \
            __builtin_amdgcn_mfma_f32_16x16x32_bf16(                          \
                af[mfq][kk], bfv[nfq][kk],                                    \
                acc[(mq) * 4 + mfq][(nq) * 2 + nfq], 0, 0, 0);                \
  __builtin_amdgcn_s_setprio(0);

  SHALF(0, 0, 0); SHALF(0, 0, 1); SHALF(0, 0, 2); SHALF(0, 0, 3);
  asm volatile("s_waitcnt vmcnt(0)" ::: "memory");
  BARX();

  for (int kt = 0; kt < 16; kt++) {
    int buf = kt & 1, nb = buf ^ 1;
    {
      DSRD(buf, 0, 0);
      if (kt < 15) { SHALF(nb, kt + 1, 0); SHALF(nb, kt + 1, 1); }
      MM(0, 0);
      BARX();
    }
    {
      DSRD(buf, 0, 1);
      if (kt < 15) { SHALF(nb, kt + 1, 2); SHALF(nb, kt + 1, 3); }
      MM(0, 1);
      BARX();
    }
    {
      DSRD(buf, 1, 0);
      MM(1, 0);
      BARX();
    }
    {
      DSRD(buf, 1, 1);
      MM(1, 1);
      asm volatile("s_waitcnt vmcnt(0)" ::: "memory");
      BARX();
    }
  }
#undef SHALF
#undef DSRD
#undef MM
#undef BARX

  unsigned short* out = (by < 4) ? qb : kb;
  float scale = (by < 4) ? qs : 1.0f;
  int cb = (by & 3) * 256;
#pragma unroll
  for (int mf = 0; mf < 8; mf++)
#pragma unroll
    for (int nf = 0; nf < 4; nf++)
#pragma unroll
      for (int r = 0; r < 4; r++) {
        int grow = m0 + wr * 128 + mf * 16 + lq * 4 + r;
        int gcol = cb + wc * 64 + nf * 16 + l15;
        out[(size_t)grow * 1024 + gcol] = f2bf(acc[mf][nf][r] * scale);
      }
}

// ---------------- flash attention (round-5 form, unchanged — verified) -------
__global__ __launch_bounds__(256, 4) void attn_k(const unsigned short* __restrict__ Q,
                                                 const unsigned short* __restrict__ K,
                                                 const unsigned short* __restrict__ VT,
                                                 unsigned short* __restrict__ ctx) {
  int f = blockIdx.x;
  int bh = ((f >> 7) << 3) | (f & 7);
  int qt = (f >> 3) & 15;
  int b = bh >> 4, h = bh & 15;
  int q0 = qt * 128;
  int tid = threadIdx.x;
  int w = tid >> 6, l = tid & 63;
  int lh = l >> 5, l31 = l & 31;

  __shared__ unsigned short Kl[2 * 64 * 64];
  __shared__ unsigned short Vl[2 * 64 * 64];

  int qrow = q0 + w * 32 + l31;
  const unsigned short* qp = Q + (size_t)(b * 2048 + qrow) * 1024 + h * 64;
  short8 qf[4];
#pragma unroll
  for (int dk = 0; dk < 4; dk++) qf[dk] = *(const short8*)(qp + dk * 16 + lh * 8);

  int key = (l31 & 7) << 4;
  int koff[4], voff[4];
#pragma unroll
  for (int dk = 0; dk < 4; dk++) koff[dk] = l31 * 128 + ((dk * 32 + lh * 16) ^ key);
#pragma unroll
  for (int tf = 0; tf < 2; tf++)
#pragma unroll
    for (int kk = 0; kk < 2; kk++)
      voff[tf * 2 + kk] = l31 * 128 + ((tf * 64 + kk * 32 + lh * 16) ^ key);

  const char* KB = (const char*)Kl;
  const char* VB = (const char*)Vl;

  f32x16 cacc[2] = {};
  float mrun = -INFINITY, lsl = 0.f;

#define STAGE(buf, tt)                                                        \
  {                                                                           \
    _Pragma("unroll") for (int i_ = 0; i_ < 2; i_++) {                        \
      int row_ = i_ * 32 + (tid >> 3), ch_ = tid & 7;                         \
      gl16(K + (size_t)(b * 2048 + (tt) + row_) * 1024 + h * 64 +             \
               ((ch_ ^ (row_ & 7)) << 3),                                     \
           (char*)Kl + (buf) * 8192 + i_ * 4096 + w * 1024);                  \
      gl16(VT + (size_t)(bh * 64 + row_) * 2048 + (tt) +                      \
               ((ch_ ^ (row_ & 7)) << 3),                                     \
           (char*)Vl + (buf) * 8192 + i_ * 4096 + w * 1024);                  \
    }                                                                         \
  }

#define COMPUTE(IMM)                                                          \
  do {                                                                        \
    f32x16 sacc[2] = {};                                                      \
    __builtin_amdgcn_s_setprio(1);                                            \
    _Pragma("unroll") for (int tf = 0; tf < 2; tf++)                          \
      _Pragma("unroll") for (int dk = 0; dk < 4; dk++) {                      \
        short8 kf = *(const short8*)(KB + koff[dk] + (IMM) + tf * 4096);      \
        sacc[tf] = __builtin_amdgcn_mfma_f32_32x32x16_bf16(kf, qf[dk],        \
                                                           sacc[tf], 0, 0, 0);\
      }                                                                       \
    __builtin_amdgcn_s_setprio(0);                                            \
    float t16[16];                                                            \
    _Pragma("unroll") for (int j = 0; j < 16; j++)                            \
      t16[j] = fmaxf(sacc[0][j], sacc[1][j]);                                 \
    float t8[8];                                                              \
    _Pragma("unroll") for (int j = 0; j < 8; j++)                             \
      t8[j] = fmaxf(t16[j], t16[j + 8]);                                      \
    float lmax = m3(m3(t8[0], t8[1], t8[2]), m3(t8[3], t8[4], t8[5]),         \
                    fmaxf(t8[6], t8[7]));                                     \
    if (!__all(lmax <= mrun + 8.f)) {                                         \
      unsigned lu = __builtin_bit_cast(unsigned, lmax);                       \
      auto rr = __builtin_amdgcn_permlane32_swap(lu, lu, false, false);       \
      float pm = fmaxf(__builtin_bit_cast(float, rr[0]),                      \
                       __builtin_bit_cast(float, rr[1]));                     \
      float mnew = fmaxf(mrun, pm);                                           \
      float alpha = hexp2(mrun - mnew);                                       \
      mrun = mnew; lsl *= alpha;                                              \
      _Pragma("unroll") for (int r = 0; r < 16; r++) {                        \
        int rowq = (r & 3) + ((r >> 2) << 3) + (lh << 2);                     \
        float ar = __shfl(alpha, rowq, 64);                                   \
        cacc[0][r] *= ar; cacc[1][r] *= ar;                                   \
      }                                                                       \
    }                                                                         \
    f32x2 negm2; negm2[0] = -mrun; negm2[1] = -mrun;                          \
    f32x2 r2; r2[0] = 0.f; r2[1] = 0.f;                                       \
    _Pragma("unroll") for (int tf = 0; tf < 2; tf++) {                        \
      unsigned pw[8];                                                         \
      _Pragma("unroll") for (int j = 0; j < 8; j++) {                         \
        f32x2 s2; s2[0] = sacc[tf][2 * j]; s2[1] = sacc[tf][2 * j + 1];       \
        f32x2 d = pkadd(s2, negm2);                                           \
        float e0 = hexp2(d[0]), e1 = hexp2(d[1]);                             \
        f32x2 e2; e2[0] = e0; e2[1] = e1;                                     \
        r2 = pkadd(r2, e2);                                                   \
        pw[j] = cvtpk2(e0, e1);                                               \
      }                                                                       \
      short8 pa[2];                                                           \
      _Pragma("unroll") for (int kk = 0; kk < 2; kk++) {                      \
        auto r02 = __builtin_amdgcn_permlane32_swap(pw[kk * 4 + 0],           \
                                                    pw[kk * 4 + 2], false, false); \
        auto r13 = __builtin_amdgcn_permlane32_swap(pw[kk * 4 + 1],           \
                                                    pw[kk * 4 + 3], false, false); \
        union { unsigned u[4]; short8 s8; } wv;                               \
        wv.u[0] = r02[0]; wv.u[1] = r13[0];                                   \
        wv.u[2] = r02[1]; wv.u[3] = r13[1];                                   \
        pa[kk] = wv.s8;                                                       \
      }                                                                       \
      __builtin_amdgcn_s_setprio(1);                                          \
      _Pragma("unroll") for (int kk = 0; kk < 2; kk++)                        \
        _Pragma("unroll") for (int df = 0; df < 2; df++) {                    \
          short8 vf = *(const short8*)(VB + voff[tf * 2 + kk] + (IMM) +       \
                                       df * 4096);                            \
          cacc[df] = __builtin_amdgcn_mfma_f32_32x32x16_bf16(pa[kk], vf,      \
                                                             cacc[df], 0, 0, 0); \
        }                                                                     \
      __builtin_amdgcn_s_setprio(0);                                          \
    }                                                                         \
    lsl += r2[0] + r2[1];                                                     \
  } while (0)

  STAGE(0, 0);
  __syncthreads();

  for (int tc2 = 0; tc2 < 16; tc2++) {
    int t0 = tc2 * 128;
    STAGE(1, t0 + 64);
    COMPUTE(0);
    __syncthreads();
    if (tc2 < 15) STAGE(0, t0 + 128);
    COMPUTE(8192);
    __syncthreads();
  }
#undef STAGE
#undef COMPUTE

  {
    unsigned lu = __builtin_bit_cast(unsigned, lsl);
    auto rr = __builtin_amdgcn_permlane32_swap(lu, lu, false, false);
    lsl = __builtin_bit_cast(float, rr[0]) + __builtin_bit_cast(float, rr[1]);
  }
  float linv = 1.f / lsl;
#pragma unroll
  for (int r = 0; r < 16; r++) {
    int rowq = (r & 3) + ((r >> 2) << 3) + (lh << 2);
    float lr = __shfl(linv, rowq, 64);
    size_t base = (size_t)(b * 2048 + q0 + w * 32 + rowq) * 1024 + h * 64 + l31;
    ctx[base]      = f2bf(cacc[0][r] * lr);
    ctx[base + 32] = f2bf(cacc[1][r] * lr);
  }
}

// ---------------- residual + LayerNorm: wave-per-row, no LDS/barrier ---------
__global__ __launch_bounds__(256) void ln_k(const unsigned short* __restrict__ ctx,
                                            const float* __restrict__ x,
                                            const float* __restrict__ wgt,
                                            const float* __restrict__ bgam,
                                            float* __restrict__ out) {
  int w = threadIdx.x >> 6, l = threadIdx.x & 63;
  size_t base = ((size_t)blockIdx.x * 4 + w) * 1024;
  float y[16];
  float s = 0.f, ss = 0.f;
#pragma unroll
  for (int j = 0; j < 4; j++) {
    int col = j * 256 + l * 4;
    ushort4 cu = *(const ushort4*)(ctx + base + col);
    float4 xv = *(const float4*)(x + base + col);
    float y0 = bf2f(cu.x) + xv.x, y1 = bf2f(cu.y) + xv.y;
    float y2 = bf2f(cu.z) + xv.z, y3 = bf2f(cu.w) + xv.w;
    y[4 * j + 0] = y0; y[4 * j + 1] = y1; y[4 * j + 2] = y2; y[4 * j + 3] = y3;
    s += (y0 + y1) + (y2 + y3);
    ss += (y0 * y0 + y1 * y1) + (y2 * y2 + y3 * y3);
  }
#pragma unroll
  for (int o = 32; o >= 1; o >>= 1) {
    s  += __shfl_xor(s, o, 64);
    ss += __shfl_xor(ss, o, 64);
  }
  float mu = s * (1.f / 1024.f);
  float var = ss * (1.f / 1024.f) - mu * mu;
  float rstd = rsqrtf(var + 1e-5f);
#pragma unroll
  for (int j = 0; j < 4; j++) {
    int col = j * 256 + l * 4;
    float4 wv = *(const float4*)(wgt + col);
    float4 bv = *(const float4*)(bgam + col);
    float4 o4;
    o4.x = (y[4 * j + 0] - mu) * rstd * wv.x + bv.x;
    o4.y = (y[4 * j + 1] - mu) * rstd * wv.y + bv.y;
    o4.z = (y[4 * j + 2] - mu) * rstd * wv.z + bv.z;
    o4.w = (y[4 * j + 3] - mu) * rstd * wv.w + bv.w;
    *(float4*)(out + base + col) = o4;
  }
}

// ---------------- launch ----------------
extern "C" void kernel_launch(void* const* d_in, const int* in_sizes, int n_in,
                              void* d_out, int out_size, void* d_ws, size_t ws_size,
                              hipStream_t stream) {
  (void)in_sizes; (void)n_in; (void)out_size; (void)ws_size;
  const float* R  = (const float*)d_in[0];
  const float* En = (const float*)d_in[1];
  const float* x  = (const float*)d_in[2];
  const float* lw = (const float*)d_in[3];
  const float* lb = (const float*)d_in[4];
  float* out = (float*)d_out;

  char* ws = (char*)d_ws;
  unsigned short* xb  = (unsigned short*)(ws);                       // 16 MB bf16 x
  unsigned short* qb  = (unsigned short*)(ws + (size_t)(16u << 20)); // 16 MB Q
  unsigned short* kb  = (unsigned short*)(ws + (size_t)(32u << 20)); // 16 MB K
  unsigned short* vt  = (unsigned short*)(ws + (size_t)(48u << 20)); // 16 MB V^T
  unsigned short* ctx = (unsigned short*)(ws + (size_t)(64u << 20)); // 16 MB context bf16
  unsigned short* rt  = (unsigned short*)(ws + (size_t)(96u << 20)); // 2 MB R^T
  unsigned short* et  = (unsigned short*)(ws + (size_t)(98u << 20)); // 2 MB E^T (contiguous)

  prep_all<<<2560, 256, 0, stream>>>(R, En, x, rt, et, vt, xb);
  gemm8<<<dim3(32, 8), 512, 0, stream>>>(xb, rt, qb, kb, 0.125f * LOG2E);
  attn_k<<<1024, 256, 0, stream>>>(qb, kb, vt, ctx);
  ln_k<<<2048, 256, 0, stream>>>(ctx, x, lw, lb, out);
}